// Round 1
// baseline (6359.815 us; speedup 1.0000x reference)
//
#include <hip/hip_runtime.h>
#include <cmath>

// ---------------------------------------------------------------------------
// Round 6 = Round 5 restructured for 2 blocks/CU:
//  - 512 blocks x 512 threads x 2 rows (was 256 x 4 rows). LDS ~40KB, VGPR<=128
//    (__launch_bounds__(512,4)) -> 2 co-resident blocks per CU fill barrier
//    stalls with the other block's waves.
//  - P4 split across even/odd thread pairs (uniform 4-tanh body + masked
//    f-tanh, shfl_xor(1) combine) so all 4 SIMDs stay active.
//  - R2 spread over all of waves 4-7 (16-float chunks, shfl_xor 2/4/8).
//  - ftanh = 1 - 2/(exp(2x)+1): clamp-free, 5 VALU ops.
// Structure otherwise identical to r5 (register-resident MFMA weights,
// lane-linear A-layout, 4 barriers/step, fW3 tiles in regs on waves 0-3).
// ---------------------------------------------------------------------------

typedef _Float16 half8 __attribute__((ext_vector_type(8)));
typedef float floatx4 __attribute__((ext_vector_type(4)));

// ws layout: f16 region (offsets in _Float16 units)
#define H_FW1 0        // [128][64]
#define H_GW1 8192     // [128][64]
#define H_FW2 16384    // [128][128]
#define H_GW2 32768    // [128][128]
#define H_FW3 49152    // [64][128]
#define H_GW3 57344    // [512][128]
#define H_RW1 122880   // [128][64]
#define H_TOTAL 131072
// f32 region (offsets in float units from ws base)
#define F_BASE 65536
#define F_RW2T (F_BASE + 0)      // [16][132]
#define F_EMBT (F_BASE + 2112)   // [64][32]
#define F_W1R0F (F_BASE + 4160)  // [128]
#define F_W1R0G (F_BASE + 4288)  // [128]
#define F_CNT 4416
#define PREP_TOTAL (H_TOTAL + F_CNT)

__global__ void prep_kernel(const float* __restrict__ fW1, const float* __restrict__ gW1,
                            const float* __restrict__ fW2, const float* __restrict__ gW2,
                            const float* __restrict__ fW3, const float* __restrict__ gW3,
                            const float* __restrict__ rW1, const float* __restrict__ rW2,
                            const float* __restrict__ embW, void* __restrict__ ws) {
  int idx = blockIdx.x * blockDim.x + threadIdx.x;
  if (idx >= PREP_TOTAL) return;
  if (idx < H_TOTAL) {
    float v;
    if (idx < H_GW1) {
      int t = idx; int c = t >> 6, k = t & 63; v = fW1[(k + 1) * 128 + c];
    } else if (idx < H_FW2) {
      int t = idx - H_GW1; int c = t >> 6, k = t & 63; v = gW1[(k + 1) * 128 + c];
    } else if (idx < H_GW2) {
      int t = idx - H_FW2; int c = t >> 7, k = t & 127; v = fW2[k * 128 + c];
    } else if (idx < H_FW3) {
      int t = idx - H_GW2; int c = t >> 7, k = t & 127; v = gW2[k * 128 + c];
    } else if (idx < H_GW3) {
      int t = idx - H_FW3; int c = t >> 7, k = t & 127; v = fW3[k * 64 + c];
    } else if (idx < H_RW1) {
      int t = idx - H_GW3; int c = t >> 7, k = t & 127; v = gW3[k * 512 + c];
    } else {
      int t = idx - H_RW1; int c = t >> 6, k = t & 63; v = rW1[k * 128 + c];
    }
    ((_Float16*)ws)[idx] = (_Float16)v;
  } else {
    int f = idx - H_TOTAL;
    float v;
    if (f < 2112) {
      int c = f / 132, k = f % 132; v = (k < 128) ? rW2[k * 16 + c] : 0.f;
    } else if (f < 4160) {
      int t = f - 2112; int c = t >> 5, k = t & 31; v = embW[k * 64 + c];
    } else if (f < 4288) {
      v = fW1[f - 4160];     // fW1 row 0 (t-row)
    } else {
      v = gW1[f - 4288];     // gW1 row 0
    }
    ((float*)ws)[F_BASE + f] = v;
  }
}

__device__ __forceinline__ float sp(float x) { return __logf(1.f + __expf(x)); }

// clamp-free tanh: exp(2x)->inf gives 1-0=1; exp(2x)->0 gives 1-2=-1.
__device__ __forceinline__ float ftanh(float x) {
  float e = __expf(2.f * x);
  return 1.f - __fdividef(2.f, e + 1.f);
}

__device__ __forceinline__ floatx4 mfma16(half8 a, half8 b, floatx4 c) {
  return __builtin_amdgcn_mfma_f32_16x16x32_f16(a, b, c, 0, 0, 0);
}

// lane-linear A-layout offset for element (m, k): seg(k>>5)*512 + ((k>>3)&3)*128 + m*8 + (k&7)
__device__ __forceinline__ int aofs(int m, int k) {
  return ((k >> 5) << 9) + (((k >> 3) & 3) << 7) + (m << 3) + (k & 7);
}

__global__ __launch_bounds__(512, 4)
void sde_main(const float* __restrict__ init_noise, const float* __restrict__ dw_noise,
              const float* __restrict__ emb_b,
              const float* __restrict__ f_b1, const float* __restrict__ f_b2,
              const float* __restrict__ f_b3, const float* __restrict__ g_b1,
              const float* __restrict__ g_b2, const float* __restrict__ g_b3,
              const float* __restrict__ r_b1, const float* __restrict__ r_b2,
              const void* __restrict__ ws, float* __restrict__ out_full,
              float* __restrict__ out_match) {
  // lane-linear f16 activation buffers (rows 2..15 hold garbage; never read)
  __shared__ __align__(16) _Float16 zseg[1024];                 // z, K=64 (2 segs)
  __shared__ __align__(16) _Float16 h1f[2048], h1g[2048];       // K=128 (4 segs)
  __shared__ __align__(16) _Float16 h2f[2048], h2g[2048];
  // f32 scratch (2 rows)
  __shared__ __align__(16) float hrs[2 * 132];    // readout hidden
  __shared__ __align__(16) float fps[2 * 68];     // f3 pre-act
  __shared__ __align__(16) float gps[2 * 528];    // g3 pre-act (16B-aligned rows)
  __shared__ __align__(16) float zb[2 * 68];      // z state f32
  __shared__ __align__(16) float dwS[2][12];
  __shared__ __align__(16) float rw2s[16 * 132];
  __shared__ float b1f[128], b1g[128], b2f[128], b2g[128], fb3[64], gb3[512];
  __shared__ float rb1[128], rb2[16], w1r0f[128], w1r0g[128];

  const int tid = threadIdx.x;
  const int w = tid >> 6;          // wave 0..7
  const int lane = tid & 63;
  const int ln16 = lane & 15;
  const int quad = lane >> 4;
  const int koff = quad * 8;
  const int wm = w & 3;
  const int b2r = blockIdx.x << 1;  // first of this block's 2 batch rows
  const _Float16* wsh = (const _Float16*)ws;
  const float* wsf = (const float*)ws;

  const float DTI = 1.0f / 511.0f;
  const float SDT = sqrtf(DTI);

  // ---- init ----
  gb3[tid] = g_b3[tid];
  if (tid < 128) {
    b1f[tid] = f_b1[tid]; b1g[tid] = g_b1[tid];
    b2f[tid] = f_b2[tid]; b2g[tid] = g_b2[tid];
    rb1[tid] = r_b1[tid];
    w1r0f[tid] = wsf[F_W1R0F + tid]; w1r0g[tid] = wsf[F_W1R0G + tid];
  }
  if (tid < 64) fb3[tid] = f_b3[tid];
  if (tid < 16) rb2[tid] = r_b2[tid];
  for (int o = tid; o < 2112; o += 512) rw2s[o] = wsf[F_RW2T + o];
  if (tid < 64) hrs[(tid >> 5) * 132 + (tid & 31)] = init_noise[b2r * 32 + tid];

  // ---- persistent B-fragments (VGPR-resident for all 511 steps) ----
  half8 Bf1[2], Bg1[2], Br1[2], B2[2][4], B3g[4][4], B3f[4];
#pragma unroll
  for (int kf = 0; kf < 2; ++kf) {
    Bf1[kf] = *(const half8*)(wsh + H_FW1 + (w * 16 + ln16) * 64 + kf * 32 + koff);
    Bg1[kf] = *(const half8*)(wsh + H_GW1 + (w * 16 + ln16) * 64 + kf * 32 + koff);
    Br1[kf] = *(const half8*)(wsh + H_RW1 + (w * 16 + ln16) * 64 + kf * 32 + koff);
  }
  const _Float16* w2b = wsh + (w < 4 ? H_FW2 : H_GW2);
#pragma unroll
  for (int i2 = 0; i2 < 2; ++i2)
#pragma unroll
    for (int kf = 0; kf < 4; ++kf)
      B2[i2][kf] = *(const half8*)(w2b + ((wm * 2 + i2) * 16 + ln16) * 128 + kf * 32 + koff);
#pragma unroll
  for (int i2 = 0; i2 < 4; ++i2)
#pragma unroll
    for (int kf = 0; kf < 4; ++kf)
      B3g[i2][kf] = *(const half8*)(wsh + H_GW3 + ((w * 4 + i2) * 16 + ln16) * 128 + kf * 32 + koff);
  {  // fW3 tile w for waves 0-3 (cols w*16+ln16 < 64)
    int cw = (w < 4 ? w : 0);
#pragma unroll
    for (int kf = 0; kf < 4; ++kf)
      B3f[kf] = *(const half8*)(wsh + H_FW3 + (cw * 16 + ln16) * 128 + kf * 32 + koff);
  }
  __syncthreads();

  // ---- z0 = init_noise @ emb_W + emb_b ----
  if (tid < 128) {
    const int rr = tid & 1, l = tid >> 1;
    const float* pe = wsf + F_EMBT + l * 32;
    float acc = emb_b[l];
#pragma unroll
    for (int c = 0; c < 8; ++c) {
      float4 a = *(const float4*)(&hrs[rr * 132 + 4 * c]);
      float4 v = *(const float4*)(pe + 4 * c);
      acc += a.x * v.x + a.y * v.y + a.z * v.z + a.w * v.w;
    }
    zb[rr * 68 + l] = acc;
    zseg[aofs(rr, l)] = (_Float16)acc;
  }
  __syncthreads();

  // R2 helper: waves 4-7 (tid>=256), readout of hrs -> out[T].
  // 2 rows x 16 outs x 8 k-chunks = 256 threads; reduce over kc (t2 bits 1-3).
  auto R2 = [&](int T) {
    const int t2 = tid - 256;
    const int r = t2 & 1, q = t2 >> 1, d = q >> 3, kc = q & 7;
    const float* ph = &hrs[r * 132 + kc * 16];
    const float* pw = &rw2s[d * 132 + kc * 16];
    float acc = 0.f;
#pragma unroll
    for (int c = 0; c < 4; ++c) {
      float4 a4 = *(const float4*)(ph + 4 * c);
      float4 w4 = *(const float4*)(pw + 4 * c);
      acc += a4.x * w4.x + a4.y * w4.y + a4.z * w4.z + a4.w * w4.w;
    }
    acc += __shfl_xor(acc, 2);
    acc += __shfl_xor(acc, 4);
    acc += __shfl_xor(acc, 8);
    if (kc == 0) {
      float v = acc + rb2[d];
      out_full[((size_t)(b2r + r) * 512 + T) * 16 + d] = v;
      if ((T & 7) == 0) out_match[((size_t)(b2r + r) * 64 + (T >> 3)) * 16 + d] = v;
    }
  };

#pragma unroll 1
  for (int i = 0; i < 511; ++i) {
    const float t_s = (float)i * DTI;

    // ---- P1: L1 (f,g) + R1, all sharing z A-frags; dW prefetch (16 thr) ----
    {
      half8 a0 = *(const half8*)(&zseg[lane * 8]);
      half8 a1 = *(const half8*)(&zseg[512 + lane * 8]);
      floatx4 cf = {0.f, 0.f, 0.f, 0.f}, cg = {0.f, 0.f, 0.f, 0.f}, cr = {0.f, 0.f, 0.f, 0.f};
      cf = mfma16(a0, Bf1[0], cf); cf = mfma16(a1, Bf1[1], cf);
      cg = mfma16(a0, Bg1[0], cg); cg = mfma16(a1, Bg1[1], cg);
      cr = mfma16(a0, Br1[0], cr); cr = mfma16(a1, Br1[1], cr);
      if (tid >= 496) {
        int n = tid - 496;   // n = 0..15  (2 rows x 8 noise dims)
        dwS[n >> 3][n & 7] = dw_noise[(size_t)i * 8192 + b2r * 8 + n] * SDT;
      }
      if (quad == 0) {
        int col = w * 16 + ln16;
        float bf = b1f[col] + t_s * w1r0f[col];
        float bg = b1g[col] + t_s * w1r0g[col];
        int ho = aofs(0, col);   // +j*8 for row j
#pragma unroll
        for (int j = 0; j < 2; ++j) {
          h1f[ho + j * 8] = (_Float16)sp(cf[j] + bf);
          h1g[ho + j * 8] = (_Float16)sp(cg[j] + bg);
          hrs[j * 132 + col] = fmaxf(cr[j] + rb1[col], 0.f);
        }
      }
    }
    __syncthreads();

    // ---- P2: L2 (waves 0-3 f, 4-7 g) + R2(T=i) on waves 4-7 ----
    {
      const _Float16* asrc = (w < 4) ? h1f : h1g;
      half8 a[4];
#pragma unroll
      for (int s = 0; s < 4; ++s) a[s] = *(const half8*)(&asrc[s * 512 + lane * 8]);
      floatx4 c0 = {0.f, 0.f, 0.f, 0.f}, c1 = {0.f, 0.f, 0.f, 0.f};
#pragma unroll
      for (int s = 0; s < 4; ++s) {
        c0 = mfma16(a[s], B2[0][s], c0);
        c1 = mfma16(a[s], B2[1][s], c1);
      }
      if (tid >= 256) R2(i);
      if (quad == 0) {
        _Float16* dst = (w < 4) ? h2f : h2g;
        const float* bb = (w < 4) ? b2f : b2g;
        int col0 = wm * 32 + ln16, col1 = col0 + 16;
        int ho0 = aofs(0, col0), ho1 = aofs(0, col1);
#pragma unroll
        for (int j = 0; j < 2; ++j) {
          dst[ho0 + j * 8] = (_Float16)sp(c0[j] + bb[col0]);
          dst[ho1 + j * 8] = (_Float16)sp(c1[j] + bb[col1]);
        }
      }
    }
    __syncthreads();

    // ---- P3: L3 g (4 tiles/wave) + L3 f on waves 0-3 (reg B-frags) ----
    {
      half8 ag[4];
#pragma unroll
      for (int s = 0; s < 4; ++s) ag[s] = *(const half8*)(&h2g[s * 512 + lane * 8]);
      floatx4 cg4[4];
#pragma unroll
      for (int i2 = 0; i2 < 4; ++i2) cg4[i2] = (floatx4){0.f, 0.f, 0.f, 0.f};
#pragma unroll
      for (int s = 0; s < 4; ++s)
#pragma unroll
        for (int i2 = 0; i2 < 4; ++i2) cg4[i2] = mfma16(ag[s], B3g[i2][s], cg4[i2]);
      floatx4 cf3 = {0.f, 0.f, 0.f, 0.f};
      if (w < 4) {
#pragma unroll
        for (int s = 0; s < 4; ++s) {
          half8 af = *(const half8*)(&h2f[s * 512 + lane * 8]);
          cf3 = mfma16(af, B3f[s], cf3);
        }
      }
      if (quad == 0) {
#pragma unroll
        for (int i2 = 0; i2 < 4; ++i2) {
          int col = (w * 4 + i2) * 16 + ln16;
#pragma unroll
          for (int j = 0; j < 2; ++j) gps[j * 528 + col] = cg4[i2][j];
        }
        if (w < 4) {
          int col = w * 16 + ln16;
#pragma unroll
          for (int j = 0; j < 2; ++j) fps[j * 68 + col] = cf3[j];
        }
      }
    }
    __syncthreads();

    // ---- P4: z += tanh(f)*dt + sum tanh(g)*dW ; even/odd pair split ----
    // pair (2t, 2t+1) handles (rr = t&1, l = t>>1): each side 4 g-terms
    // (uniform), even side additionally the f-term (exec-masked once).
    if (tid < 256) {
      const int odd = tid & 1, h = tid >> 1;
      const int rr = h & 1, l = h >> 1;
      const int o4 = odd * 4;
      float4 g = *(const float4*)(&gps[rr * 528 + l * 8 + o4]);
      const float* gb = &gb3[l * 8 + o4];
      const float* dw = &dwS[rr][o4];
      float acc = ftanh(g.x + gb[0]) * dw[0]
                + ftanh(g.y + gb[1]) * dw[1]
                + ftanh(g.z + gb[2]) * dw[2]
                + ftanh(g.w + gb[3]) * dw[3];
      if (!odd) acc += ftanh(fps[rr * 68 + l] + fb3[l]) * DTI;
      acc += __shfl_xor(acc, 1);
      if (!odd) {
        float zn = zb[rr * 68 + l] + acc;
        zb[rr * 68 + l] = zn;
        zseg[aofs(rr, l)] = (_Float16)zn;
      }
    }
    __syncthreads();
  }

  // ---- final readout T=511 ----
  {
    half8 a0 = *(const half8*)(&zseg[lane * 8]);
    half8 a1 = *(const half8*)(&zseg[512 + lane * 8]);
    floatx4 cr = {0.f, 0.f, 0.f, 0.f};
    cr = mfma16(a0, Br1[0], cr); cr = mfma16(a1, Br1[1], cr);
    if (quad == 0) {
      int col = w * 16 + ln16;
#pragma unroll
      for (int j = 0; j < 2; ++j) hrs[j * 132 + col] = fmaxf(cr[j] + rb1[col], 0.f);
    }
  }
  __syncthreads();
  if (tid >= 256) R2(511);
}

extern "C" void kernel_launch(void* const* d_in, const int* in_sizes, int n_in,
                              void* d_out, int out_size, void* d_ws, size_t ws_size,
                              hipStream_t stream) {
  (void)in_sizes; (void)n_in; (void)out_size; (void)ws_size;
  const float* init_noise = (const float*)d_in[0];
  const float* dw_noise   = (const float*)d_in[1];
  const float* emb_W      = (const float*)d_in[3];
  const float* emb_b      = (const float*)d_in[4];
  const float* f_W1       = (const float*)d_in[5];
  const float* f_b1       = (const float*)d_in[6];
  const float* f_W2       = (const float*)d_in[7];
  const float* f_b2       = (const float*)d_in[8];
  const float* f_W3       = (const float*)d_in[9];
  const float* f_b3       = (const float*)d_in[10];
  const float* g_W1       = (const float*)d_in[11];
  const float* g_b1       = (const float*)d_in[12];
  const float* g_W2       = (const float*)d_in[13];
  const float* g_b2       = (const float*)d_in[14];
  const float* g_W3       = (const float*)d_in[15];
  const float* g_b3       = (const float*)d_in[16];
  const float* r_W1       = (const float*)d_in[17];
  const float* r_b1       = (const float*)d_in[18];
  const float* r_W2       = (const float*)d_in[19];
  const float* r_b2       = (const float*)d_in[20];
  float* out_full = (float*)d_out;
  float* out_match = out_full + (size_t)1024 * 512 * 16;

  hipLaunchKernelGGL(prep_kernel, dim3((PREP_TOTAL + 255) / 256), dim3(256), 0, stream,
                     f_W1, g_W1, f_W2, g_W2, f_W3, g_W3, r_W1, r_W2, emb_W, d_ws);
  hipLaunchKernelGGL(sde_main, dim3(512), dim3(512), 0, stream,
                     init_noise, dw_noise, emb_b, f_b1, f_b2, f_b3,
                     g_b1, g_b2, g_b3, r_b1, r_b2, d_ws, out_full, out_match);
}

// Round 2
// 1643.836 us; speedup vs baseline: 3.8689x; 3.8689x over previous
//
#include <hip/hip_runtime.h>
#include <cmath>

// ---------------------------------------------------------------------------
// Round 7. Post-mortem of r6: __launch_bounds__(512,4) capped unified regs at
// 128 while the 8-wave distribution needs ~136 VGPRs of persistent weight
// fragments -> weight stash spilled to scratch -> FETCH_SIZE 9.4MB -> 16.9GB,
// memory-bound at 2.7 TB/s, 4.3x slower. Occupancy DID hit 47%, validating
// the mechanism; 2x 8-wave blocks/CU is arithmetically impossible with
// register-resident weights.
//
// r7: ONE 16-wave (1024-thread) block per CU, 256 blocks x 4 rows. Weights
// split across 16 waves -> 18 half8 = 72 persistent VGPRs (fits the 128 cap).
//   P1: wave w<8: fW1 tile w -> h1f ; w>=8: gW1 tile (w-8) -> h1g. +dW pref.
//   P2: one L2 tile/wave (f2 w<8 -> h2f, g2 w>=8 -> h2g); waves 8-15 also
//       compute r1 (zseg still valid) -> hrs.
//   P3: two gW3 tiles/wave -> gps; waves 0-3 also fW3 tile (U1b/U1c overlay,
//       unused by them for r1) -> fps.
//   P4: tid<512: pair-split z-update (r6-proven); tid in [512,768): R2(i)
//       (hrs untouched until next P1). 4 barriers/step unchanged.
// Clamp-free ftanh kept from r6. Lane-linear A-layout + reg weights from r5.
// ---------------------------------------------------------------------------

typedef _Float16 half8 __attribute__((ext_vector_type(8)));
typedef float floatx4 __attribute__((ext_vector_type(4)));

// ws layout: f16 region (offsets in _Float16 units)
#define H_FW1 0        // [128][64]
#define H_GW1 8192     // [128][64]
#define H_FW2 16384    // [128][128]
#define H_GW2 32768    // [128][128]
#define H_FW3 49152    // [64][128]
#define H_GW3 57344    // [512][128]
#define H_RW1 122880   // [128][64]
#define H_TOTAL 131072
// f32 region (offsets in float units from ws base)
#define F_BASE 65536
#define F_RW2T (F_BASE + 0)      // [16][132]
#define F_EMBT (F_BASE + 2112)   // [64][32]
#define F_W1R0F (F_BASE + 4160)  // [128]
#define F_W1R0G (F_BASE + 4288)  // [128]
#define F_CNT 4416
#define PREP_TOTAL (H_TOTAL + F_CNT)

__global__ void prep_kernel(const float* __restrict__ fW1, const float* __restrict__ gW1,
                            const float* __restrict__ fW2, const float* __restrict__ gW2,
                            const float* __restrict__ fW3, const float* __restrict__ gW3,
                            const float* __restrict__ rW1, const float* __restrict__ rW2,
                            const float* __restrict__ embW, void* __restrict__ ws) {
  int idx = blockIdx.x * blockDim.x + threadIdx.x;
  if (idx >= PREP_TOTAL) return;
  if (idx < H_TOTAL) {
    float v;
    if (idx < H_GW1) {
      int t = idx; int c = t >> 6, k = t & 63; v = fW1[(k + 1) * 128 + c];
    } else if (idx < H_FW2) {
      int t = idx - H_GW1; int c = t >> 6, k = t & 63; v = gW1[(k + 1) * 128 + c];
    } else if (idx < H_GW2) {
      int t = idx - H_FW2; int c = t >> 7, k = t & 127; v = fW2[k * 128 + c];
    } else if (idx < H_FW3) {
      int t = idx - H_GW2; int c = t >> 7, k = t & 127; v = gW2[k * 128 + c];
    } else if (idx < H_GW3) {
      int t = idx - H_FW3; int c = t >> 7, k = t & 127; v = fW3[k * 64 + c];
    } else if (idx < H_RW1) {
      int t = idx - H_GW3; int c = t >> 7, k = t & 127; v = gW3[k * 512 + c];
    } else {
      int t = idx - H_RW1; int c = t >> 6, k = t & 63; v = rW1[k * 128 + c];
    }
    ((_Float16*)ws)[idx] = (_Float16)v;
  } else {
    int f = idx - H_TOTAL;
    float v;
    if (f < 2112) {
      int c = f / 132, k = f % 132; v = (k < 128) ? rW2[k * 16 + c] : 0.f;
    } else if (f < 4160) {
      int t = f - 2112; int c = t >> 5, k = t & 31; v = embW[k * 64 + c];
    } else if (f < 4288) {
      v = fW1[f - 4160];     // fW1 row 0 (t-row)
    } else {
      v = gW1[f - 4288];     // gW1 row 0
    }
    ((float*)ws)[F_BASE + f] = v;
  }
}

__device__ __forceinline__ float sp(float x) { return __logf(1.f + __expf(x)); }

// clamp-free tanh: exp(2x)->inf gives 1-0=1; exp(2x)->0 gives 1-2=-1.
__device__ __forceinline__ float ftanh(float x) {
  float e = __expf(2.f * x);
  return 1.f - __fdividef(2.f, e + 1.f);
}

__device__ __forceinline__ floatx4 mfma16(half8 a, half8 b, floatx4 c) {
  return __builtin_amdgcn_mfma_f32_16x16x32_f16(a, b, c, 0, 0, 0);
}

// lane-linear A-layout offset for element (m, k): seg(k>>5)*512 + ((k>>3)&3)*128 + m*8 + (k&7)
__device__ __forceinline__ int aofs(int m, int k) {
  return ((k >> 5) << 9) + (((k >> 3) & 3) << 7) + (m << 3) + (k & 7);
}

__global__ __launch_bounds__(1024, 4)
void sde_main(const float* __restrict__ init_noise, const float* __restrict__ dw_noise,
              const float* __restrict__ emb_b,
              const float* __restrict__ f_b1, const float* __restrict__ f_b2,
              const float* __restrict__ f_b3, const float* __restrict__ g_b1,
              const float* __restrict__ g_b2, const float* __restrict__ g_b3,
              const float* __restrict__ r_b1, const float* __restrict__ r_b2,
              const void* __restrict__ ws, float* __restrict__ out_full,
              float* __restrict__ out_match) {
  // lane-linear f16 activation buffers (rows 4..15 hold garbage; never read)
  __shared__ __align__(16) _Float16 zseg[1024];                 // z, K=64 (2 segs)
  __shared__ __align__(16) _Float16 h1f[2048], h1g[2048];       // K=128 (4 segs)
  __shared__ __align__(16) _Float16 h2f[2048], h2g[2048];
  // f32 scratch (4 rows)
  __shared__ __align__(16) float hrs[4 * 132];    // readout hidden
  __shared__ __align__(16) float fps[4 * 68];     // f3 pre-act
  __shared__ __align__(16) float gps[4 * 528];    // g3 pre-act (16B-aligned rows)
  __shared__ __align__(16) float zb[4 * 68];      // z state f32
  __shared__ __align__(16) float dwS[4][12];
  __shared__ __align__(16) float rw2s[16 * 132];
  __shared__ float b1f[128], b1g[128], b2f[128], b2g[128], fb3[64], gb3[512];
  __shared__ float rb1[128], rb2[16], w1r0f[128], w1r0g[128];

  const int tid = threadIdx.x;
  const int w = tid >> 6;          // wave 0..15
  const int lane = tid & 63;
  const int ln16 = lane & 15;
  const int quad = lane >> 4;
  const int koff = quad * 8;
  const int b4 = blockIdx.x << 2;  // first of this block's 4 batch rows
  const _Float16* wsh = (const _Float16*)ws;
  const float* wsf = (const float*)ws;

  const float DTI = 1.0f / 511.0f;
  const float SDT = sqrtf(DTI);

  // ---- init ----
  if (tid < 512) gb3[tid] = g_b3[tid];
  if (tid < 128) {
    b1f[tid] = f_b1[tid]; b1g[tid] = g_b1[tid];
    b2f[tid] = f_b2[tid]; b2g[tid] = g_b2[tid];
    rb1[tid] = r_b1[tid];
    w1r0f[tid] = wsf[F_W1R0F + tid]; w1r0g[tid] = wsf[F_W1R0G + tid];
  }
  if (tid < 64) fb3[tid] = f_b3[tid];
  if (tid < 16) rb2[tid] = r_b2[tid];
  for (int o = tid; o < 2112; o += 1024) rw2s[o] = wsf[F_RW2T + o];
  if (tid < 128) hrs[(tid >> 5) * 132 + (tid & 31)] = init_noise[b4 * 32 + tid];

  // ---- persistent B-fragments: 18 half8 = 72 VGPRs/thread ----
  // U1a: w<8 -> fW1 tile w   ; w>=8 -> gW1 tile (w-8)      (P1)
  // U1b: w<8 -> fW3 frag 0,1 ; w>=8 -> rW1 tile (w-8)      (P3 / P2+final)
  // U1c: fW3 frag 2,3 (used by waves 0-3 only)
  // B2 : w<8 -> fW2 tile w   ; w>=8 -> gW2 tile (w-8)      (P2)
  // B3g: gW3 tiles 2w, 2w+1                                 (P3)
  half8 U1a[2], U1b[2], U1c[2], B2[4], B3g[2][4];
  {
    const int t1 = (w & 7) * 16 + ln16;
    const int t3 = (w & 3) * 16 + ln16;
    const _Float16* ab = wsh + (w < 8 ? H_FW1 : H_GW1);
#pragma unroll
    for (int kf = 0; kf < 2; ++kf)
      U1a[kf] = *(const half8*)(ab + t1 * 64 + kf * 32 + koff);
    if (w >= 8) {
#pragma unroll
      for (int kf = 0; kf < 2; ++kf)
        U1b[kf] = *(const half8*)(wsh + H_RW1 + t1 * 64 + kf * 32 + koff);
    } else {
#pragma unroll
      for (int kf = 0; kf < 2; ++kf)
        U1b[kf] = *(const half8*)(wsh + H_FW3 + t3 * 128 + kf * 32 + koff);
    }
#pragma unroll
    for (int kf = 0; kf < 2; ++kf)
      U1c[kf] = *(const half8*)(wsh + H_FW3 + t3 * 128 + (2 + kf) * 32 + koff);
    const _Float16* w2b = wsh + (w < 8 ? H_FW2 : H_GW2);
#pragma unroll
    for (int kf = 0; kf < 4; ++kf)
      B2[kf] = *(const half8*)(w2b + t1 * 128 + kf * 32 + koff);
#pragma unroll
    for (int i2 = 0; i2 < 2; ++i2)
#pragma unroll
      for (int kf = 0; kf < 4; ++kf)
        B3g[i2][kf] = *(const half8*)(wsh + H_GW3 + ((2 * w + i2) * 16 + ln16) * 128 + kf * 32 + koff);
  }
  __syncthreads();

  // ---- z0 = init_noise @ emb_W + emb_b ----
  if (tid < 256) {
    const int rr = tid & 3, l = tid >> 2;
    const float* pe = wsf + F_EMBT + l * 32;
    float acc = emb_b[l];
#pragma unroll
    for (int c = 0; c < 8; ++c) {
      float4 a = *(const float4*)(&hrs[rr * 132 + 4 * c]);
      float4 v = *(const float4*)(pe + 4 * c);
      acc += a.x * v.x + a.y * v.y + a.z * v.z + a.w * v.w;
    }
    zb[rr * 68 + l] = acc;
    zseg[aofs(rr, l)] = (_Float16)acc;
  }
  __syncthreads();

  // R2 helper: tid in [512,768) (waves 8-11). 4 rows x 16 outs x 4 k-chunks.
  auto R2 = [&](int T) {
    const int t2 = tid - 512;
    const int r = t2 & 3, q2 = t2 >> 2, d = q2 >> 2, kk = q2 & 3;
    const float* ph = &hrs[r * 132 + kk * 32];
    const float* pw = &rw2s[d * 132 + kk * 32];
    float acc = 0.f;
#pragma unroll
    for (int c = 0; c < 8; ++c) {
      float4 a4 = *(const float4*)(ph + 4 * c);
      float4 w4 = *(const float4*)(pw + 4 * c);
      acc += a4.x * w4.x + a4.y * w4.y + a4.z * w4.z + a4.w * w4.w;
    }
    acc += __shfl_xor(acc, 4);
    acc += __shfl_xor(acc, 8);
    if (kk == 0) {
      float v = acc + rb2[d];
      out_full[((size_t)(b4 + r) * 512 + T) * 16 + d] = v;
      if ((T & 7) == 0) out_match[((size_t)(b4 + r) * 64 + (T >> 3)) * 16 + d] = v;
    }
  };

#pragma unroll 1
  for (int i = 0; i < 511; ++i) {
    const float t_s = (float)i * DTI;

    // ---- P1: L1, one tile per wave (f on w<8, g on w>=8); dW prefetch ----
    {
      half8 a0 = *(const half8*)(&zseg[lane * 8]);
      half8 a1 = *(const half8*)(&zseg[512 + lane * 8]);
      floatx4 c = {0.f, 0.f, 0.f, 0.f};
      c = mfma16(a0, U1a[0], c); c = mfma16(a1, U1a[1], c);
      if (tid >= 992) {
        int n = tid - 992;   // 32 threads: 4 rows x 8 noise dims
        dwS[n >> 3][n & 7] = dw_noise[(size_t)i * 8192 + b4 * 8 + n] * SDT;
      }
      if (quad == 0) {
        int col = (w & 7) * 16 + ln16;
        int ho = aofs(0, col);
        if (w < 8) {
          float bf = b1f[col] + t_s * w1r0f[col];
#pragma unroll
          for (int j = 0; j < 4; ++j) h1f[ho + j * 8] = (_Float16)sp(c[j] + bf);
        } else {
          float bg = b1g[col] + t_s * w1r0g[col];
#pragma unroll
          for (int j = 0; j < 4; ++j) h1g[ho + j * 8] = (_Float16)sp(c[j] + bg);
        }
      }
    }
    __syncthreads();

    // ---- P2: one L2 tile per wave; waves 8-15 also r1 (zseg still valid) ----
    {
      const _Float16* asrc = (w < 8) ? h1f : h1g;
      half8 a[4];
#pragma unroll
      for (int s = 0; s < 4; ++s) a[s] = *(const half8*)(&asrc[s * 512 + lane * 8]);
      floatx4 c0 = {0.f, 0.f, 0.f, 0.f};
#pragma unroll
      for (int s = 0; s < 4; ++s) c0 = mfma16(a[s], B2[s], c0);
      floatx4 cr = {0.f, 0.f, 0.f, 0.f};
      if (w >= 8) {
        half8 z0f = *(const half8*)(&zseg[lane * 8]);
        half8 z1f = *(const half8*)(&zseg[512 + lane * 8]);
        cr = mfma16(z0f, U1b[0], cr); cr = mfma16(z1f, U1b[1], cr);
      }
      if (quad == 0) {
        int col = (w & 7) * 16 + ln16;
        int ho = aofs(0, col);
        if (w < 8) {
#pragma unroll
          for (int j = 0; j < 4; ++j) h2f[ho + j * 8] = (_Float16)sp(c0[j] + b2f[col]);
        } else {
#pragma unroll
          for (int j = 0; j < 4; ++j) {
            h2g[ho + j * 8] = (_Float16)sp(c0[j] + b2g[col]);
            hrs[j * 132 + col] = fmaxf(cr[j] + rb1[col], 0.f);
          }
        }
      }
    }
    __syncthreads();

    // ---- P3: 2 gW3 tiles per wave; waves 0-3 also fW3 tile ----
    {
      half8 ag[4];
#pragma unroll
      for (int s = 0; s < 4; ++s) ag[s] = *(const half8*)(&h2g[s * 512 + lane * 8]);
      floatx4 cg0 = {0.f, 0.f, 0.f, 0.f}, cg1 = {0.f, 0.f, 0.f, 0.f};
#pragma unroll
      for (int s = 0; s < 4; ++s) {
        cg0 = mfma16(ag[s], B3g[0][s], cg0);
        cg1 = mfma16(ag[s], B3g[1][s], cg1);
      }
      if (quad == 0) {
        int c0 = (2 * w) * 16 + ln16, c1 = c0 + 16;
#pragma unroll
        for (int j = 0; j < 4; ++j) {
          gps[j * 528 + c0] = cg0[j];
          gps[j * 528 + c1] = cg1[j];
        }
      }
      if (w < 4) {
        floatx4 cf3 = {0.f, 0.f, 0.f, 0.f};
#pragma unroll
        for (int s = 0; s < 4; ++s) {
          half8 af = *(const half8*)(&h2f[s * 512 + lane * 8]);
          cf3 = mfma16(af, (s < 2 ? U1b[s] : U1c[s - 2]), cf3);
        }
        if (quad == 0) {
          int col = w * 16 + ln16;
#pragma unroll
          for (int j = 0; j < 4; ++j) fps[j * 68 + col] = cf3[j];
        }
      }
    }
    __syncthreads();

    // ---- P4: pair-split z-update (tid<512) + R2(i) (waves 8-11) ----
    if (tid < 512) {
      const int odd = tid & 1, h = tid >> 1;   // h in [0,256)
      const int rr = h & 3, l = h >> 2;        // 4 rows x 64 cols
      const int o4 = odd * 4;
      float4 g = *(const float4*)(&gps[rr * 528 + l * 8 + o4]);
      const float* gb = &gb3[l * 8 + o4];
      const float* dw = &dwS[rr][o4];
      float acc = ftanh(g.x + gb[0]) * dw[0]
                + ftanh(g.y + gb[1]) * dw[1]
                + ftanh(g.z + gb[2]) * dw[2]
                + ftanh(g.w + gb[3]) * dw[3];
      if (!odd) acc += ftanh(fps[rr * 68 + l] + fb3[l]) * DTI;
      acc += __shfl_xor(acc, 1);
      if (!odd) {
        float zn = zb[rr * 68 + l] + acc;
        zb[rr * 68 + l] = zn;
        zseg[aofs(rr, l)] = (_Float16)zn;
      }
    } else if (tid < 768) {
      R2(i);
    }
    __syncthreads();
  }

  // ---- final readout T=511 ----
  if (w >= 8) {
    half8 a0 = *(const half8*)(&zseg[lane * 8]);
    half8 a1 = *(const half8*)(&zseg[512 + lane * 8]);
    floatx4 cr = {0.f, 0.f, 0.f, 0.f};
    cr = mfma16(a0, U1b[0], cr); cr = mfma16(a1, U1b[1], cr);
    if (quad == 0) {
      int col = (w & 7) * 16 + ln16;
#pragma unroll
      for (int j = 0; j < 4; ++j) hrs[j * 132 + col] = fmaxf(cr[j] + rb1[col], 0.f);
    }
  }
  __syncthreads();
  if (tid >= 512 && tid < 768) R2(511);
}

extern "C" void kernel_launch(void* const* d_in, const int* in_sizes, int n_in,
                              void* d_out, int out_size, void* d_ws, size_t ws_size,
                              hipStream_t stream) {
  (void)in_sizes; (void)n_in; (void)out_size; (void)ws_size;
  const float* init_noise = (const float*)d_in[0];
  const float* dw_noise   = (const float*)d_in[1];
  const float* emb_W      = (const float*)d_in[3];
  const float* emb_b      = (const float*)d_in[4];
  const float* f_W1       = (const float*)d_in[5];
  const float* f_b1       = (const float*)d_in[6];
  const float* f_W2       = (const float*)d_in[7];
  const float* f_b2       = (const float*)d_in[8];
  const float* f_W3       = (const float*)d_in[9];
  const float* f_b3       = (const float*)d_in[10];
  const float* g_W1       = (const float*)d_in[11];
  const float* g_b1       = (const float*)d_in[12];
  const float* g_W2       = (const float*)d_in[13];
  const float* g_b2       = (const float*)d_in[14];
  const float* g_W3       = (const float*)d_in[15];
  const float* g_b3       = (const float*)d_in[16];
  const float* r_W1       = (const float*)d_in[17];
  const float* r_b1       = (const float*)d_in[18];
  const float* r_W2       = (const float*)d_in[19];
  const float* r_b2       = (const float*)d_in[20];
  float* out_full = (float*)d_out;
  float* out_match = out_full + (size_t)1024 * 512 * 16;

  hipLaunchKernelGGL(prep_kernel, dim3((PREP_TOTAL + 255) / 256), dim3(256), 0, stream,
                     f_W1, g_W1, f_W2, g_W2, f_W3, g_W3, r_W1, r_W2, emb_W, d_ws);
  hipLaunchKernelGGL(sde_main, dim3(256), dim3(1024), 0, stream,
                     init_noise, dw_noise, emb_b, f_b1, f_b2, f_b3,
                     g_b1, g_b2, g_b3, r_b1, r_b2, d_ws, out_full, out_match);
}

// Round 3
// 1140.699 us; speedup vs baseline: 5.5754x; 1.4411x over previous
//
#include <hip/hip_runtime.h>
#include <cmath>

// ---------------------------------------------------------------------------
// Round 8. Post-mortem r6/r7: kernel is VALU-ISSUE-bound (~4000 SIMD-cyc/step
// issue in both r5 2-wave/SIMD and r7 4-wave/SIMD configs; doubling waves
// didn't help -> not latency-bound). r8 returns to the r5 shape (256 blocks x
// 512 threads x 4 rows, 8-wave weight split, 1471us baseline) and cuts issued
// instructions:
//  1) Quad-duplication: A-frags read with row m&3 (LDS broadcast, free) ->
//     every quad's C regs j=0..3 hold real rows 0..3 -> activations/epilogues
//     full-wave (1 op/lane) instead of quad0-masked (4 ops/lane). Sub-k bank
//     shift keeps duplicated reads 2-way (free).
//  2) dW prefetch pipeline: load step i+1 at P1-start, stash to dwS[(i+1)&1]
//     in P2, consume dwS[i&1] in P4 -> HBM latency off the barrier path.
//  3) All step-invariant per-lane constants preloaded to VGPRs (biases,
//     t-row weights, gb3/fb3/rb2, z f32 state, LDS addresses). 6 LDS bias
//     arrays dropped.
// Structure: 4 barriers/step, register-resident MFMA weights, R1 in P1,
// R2 in P2 (waves 4-7), pair-split P4 on all 512 threads.
// ---------------------------------------------------------------------------

typedef _Float16 half8 __attribute__((ext_vector_type(8)));
typedef float floatx4 __attribute__((ext_vector_type(4)));

// ws layout: f16 region (offsets in _Float16 units)
#define H_FW1 0        // [128][64]
#define H_GW1 8192     // [128][64]
#define H_FW2 16384    // [128][128]
#define H_GW2 32768    // [128][128]
#define H_FW3 49152    // [64][128]
#define H_GW3 57344    // [512][128]
#define H_RW1 122880   // [128][64]
#define H_TOTAL 131072
// f32 region (offsets in float units from ws base)
#define F_BASE 65536
#define F_RW2T (F_BASE + 0)      // [16][132]
#define F_EMBT (F_BASE + 2112)   // [64][32]
#define F_W1R0F (F_BASE + 4160)  // [128]
#define F_W1R0G (F_BASE + 4288)  // [128]
#define F_CNT 4416
#define PREP_TOTAL (H_TOTAL + F_CNT)

__global__ void prep_kernel(const float* __restrict__ fW1, const float* __restrict__ gW1,
                            const float* __restrict__ fW2, const float* __restrict__ gW2,
                            const float* __restrict__ fW3, const float* __restrict__ gW3,
                            const float* __restrict__ rW1, const float* __restrict__ rW2,
                            const float* __restrict__ embW, void* __restrict__ ws) {
  int idx = blockIdx.x * blockDim.x + threadIdx.x;
  if (idx >= PREP_TOTAL) return;
  if (idx < H_TOTAL) {
    float v;
    if (idx < H_GW1) {
      int t = idx; int c = t >> 6, k = t & 63; v = fW1[(k + 1) * 128 + c];
    } else if (idx < H_FW2) {
      int t = idx - H_GW1; int c = t >> 6, k = t & 63; v = gW1[(k + 1) * 128 + c];
    } else if (idx < H_GW2) {
      int t = idx - H_FW2; int c = t >> 7, k = t & 127; v = fW2[k * 128 + c];
    } else if (idx < H_FW3) {
      int t = idx - H_GW2; int c = t >> 7, k = t & 127; v = gW2[k * 128 + c];
    } else if (idx < H_GW3) {
      int t = idx - H_FW3; int c = t >> 7, k = t & 127; v = fW3[k * 64 + c];
    } else if (idx < H_RW1) {
      int t = idx - H_GW3; int c = t >> 7, k = t & 127; v = gW3[k * 512 + c];
    } else {
      int t = idx - H_RW1; int c = t >> 6, k = t & 63; v = rW1[k * 128 + c];
    }
    ((_Float16*)ws)[idx] = (_Float16)v;
  } else {
    int f = idx - H_TOTAL;
    float v;
    if (f < 2112) {
      int c = f / 132, k = f % 132; v = (k < 128) ? rW2[k * 16 + c] : 0.f;
    } else if (f < 4160) {
      int t = f - 2112; int c = t >> 5, k = t & 31; v = embW[k * 64 + c];
    } else if (f < 4288) {
      v = fW1[f - 4160];     // fW1 row 0 (t-row)
    } else {
      v = gW1[f - 4288];     // gW1 row 0
    }
    ((float*)ws)[F_BASE + f] = v;
  }
}

__device__ __forceinline__ float sp(float x) { return __logf(1.f + __expf(x)); }

// clamp-free tanh: exp(2x)->inf gives 1-0=1; exp(2x)->0 gives 1-2=-1.
__device__ __forceinline__ float ftanh(float x) {
  float e = __expf(2.f * x);
  return 1.f - __fdividef(2.f, e + 1.f);
}

__device__ __forceinline__ floatx4 mfma16(half8 a, half8 b, floatx4 c) {
  return __builtin_amdgcn_mfma_f32_16x16x32_f16(a, b, c, 0, 0, 0);
}

// lane-linear A-layout with sub-k bank shift.
// element (m,k): seg(k>>5)*512 + subk*128 + (subk&1)*32 + m*8 + (k&7)
__device__ __forceinline__ int aofs2(int m, int k) {
  int subk = (k >> 3) & 3;
  return ((k >> 5) << 9) + (subk << 7) + ((subk & 1) << 5) + (m << 3) + (k & 7);
}

// select element `quad` of a floatx4 with static indices (rule #20 safe)
__device__ __forceinline__ float qsel(floatx4 c, int quad) {
  float v01 = (quad & 1) ? c[1] : c[0];
  float v23 = (quad & 1) ? c[3] : c[2];
  return (quad & 2) ? v23 : v01;
}

__global__ __launch_bounds__(512, 2)
void sde_main(const float* __restrict__ init_noise, const float* __restrict__ dw_noise,
              const float* __restrict__ emb_b,
              const float* __restrict__ f_b1, const float* __restrict__ f_b2,
              const float* __restrict__ f_b3, const float* __restrict__ g_b1,
              const float* __restrict__ g_b2, const float* __restrict__ g_b3,
              const float* __restrict__ r_b1, const float* __restrict__ r_b2,
              const void* __restrict__ ws, float* __restrict__ out_full,
              float* __restrict__ out_match) {
  // lane-linear f16 activation buffers (only rows 0-3 stored; duplicated reads)
  __shared__ __align__(16) _Float16 zseg[1024];                 // z, K=64 (2 segs)
  __shared__ __align__(16) _Float16 h1f[2048], h1g[2048];       // K=128 (4 segs)
  __shared__ __align__(16) _Float16 h2f[2048], h2g[2048];
  // f32 scratch
  __shared__ __align__(16) float hrs[4 * 144];    // readout hidden
  __shared__ __align__(16) float fps[4 * 80];     // f3 pre-act
  __shared__ __align__(16) float gps[4 * 532];    // g3 pre-act
  __shared__ __align__(16) float zb[4 * 68];      // z state f32 (init staging)
  __shared__ __align__(16) float dwS[2][4][12];   // double-buffered dW
  __shared__ __align__(16) float rw2s[16 * 132];

  const int tid = threadIdx.x;
  const int w = tid >> 6;          // wave 0..7
  const int lane = tid & 63;
  const int ln16 = lane & 15;
  const int quad = lane >> 4;
  const int koff = quad * 8;
  const int wm = w & 3;
  const int b4 = blockIdx.x << 2;
  const _Float16* wsh = (const _Float16*)ws;
  const float* wsf = (const float*)ws;

  const float DTI = 1.0f / 511.0f;
  const float SDT = sqrtf(DTI);

  // ---- step-invariant per-lane constants (registers) ----
  const int col1 = w * 16 + ln16;                 // P1/R1 column
  const float b1fv = f_b1[col1], b1gv = g_b1[col1];
  const float w1fv = wsf[F_W1R0F + col1], w1gv = wsf[F_W1R0G + col1];
  const float rb1v = r_b1[col1];
  const int colA = wm * 32 + ln16, colB = colA + 16;  // P2 columns
  const float* bsrc2 = (w < 4) ? f_b2 : g_b2;
  const float b2vA = bsrc2[colA], b2vB = bsrc2[colB];
  // duplicated A-read offset (within a 512-f16 seg)
  const int ra = ((lane >> 4) << 7) + (((lane >> 4) & 1) << 5) + ((lane & 3) << 3);
  // write addresses
  const int haddr1 = aofs2(quad, col1);
  const int haddr2A = aofs2(quad, colA), haddr2B = aofs2(quad, colB);
  const int hrsaddr = quad * 144 + col1;
  const int gpsbase = quad * 532 + w * 64 + ln16; // + i2*16
  const int fpsaddr = quad * 80 + (w & 3) * 16 + ln16;
  // P4 (pair-split over all 512 threads)
  const int odd = tid & 1, hh = tid >> 1;
  const int rr4 = hh & 3, l4 = hh >> 2, o4 = odd * 4;
  const int gofs = rr4 * 532 + l4 * 8 + o4;
  const int dwofs = rr4 * 12 + o4;                // + 48*(i&1)
  const int zwaddr = aofs2(rr4, l4);
  const int zbofs = rr4 * 68 + l4;
  const float fbv = f_b3[l4];
  const float4 gbv4 = *(const float4*)(&g_b3[l4 * 8 + o4]);
  // R2 constants (threads 256-511; harmless for others)
  const int t2 = tid & 255;
  const int r2r = t2 & 3, q2 = t2 >> 2, r2d = q2 >> 2, r2kk = q2 & 3;
  const float rb2v = r_b2[r2d];
  const size_t ofull = ((size_t)(b4 + r2r) * 512) * 16 + r2d;
  const size_t omatch = ((size_t)(b4 + r2r) * 64) * 16 + r2d;

  // ---- init LDS ----
  for (int o = tid; o < 2112; o += 512) rw2s[o] = wsf[F_RW2T + o];
  if (tid < 128) hrs[(tid >> 5) * 144 + (tid & 31)] = init_noise[b4 * 32 + tid];
  if (w == 7 && lane < 32)
    dwS[0][lane >> 3][lane & 7] = dw_noise[b4 * 8 + lane] * SDT;

  // ---- persistent B-fragments (VGPR-resident for all 511 steps) ----
  half8 Bf1[2], Bg1[2], Br1[2], B2[2][4], B3g[4][4], B3f[4];
#pragma unroll
  for (int kf = 0; kf < 2; ++kf) {
    Bf1[kf] = *(const half8*)(wsh + H_FW1 + col1 * 64 + kf * 32 + koff);
    Bg1[kf] = *(const half8*)(wsh + H_GW1 + col1 * 64 + kf * 32 + koff);
    Br1[kf] = *(const half8*)(wsh + H_RW1 + col1 * 64 + kf * 32 + koff);
  }
  const _Float16* w2b = wsh + (w < 4 ? H_FW2 : H_GW2);
#pragma unroll
  for (int i2 = 0; i2 < 2; ++i2)
#pragma unroll
    for (int kf = 0; kf < 4; ++kf)
      B2[i2][kf] = *(const half8*)(w2b + ((wm * 2 + i2) * 16 + ln16) * 128 + kf * 32 + koff);
#pragma unroll
  for (int i2 = 0; i2 < 4; ++i2)
#pragma unroll
    for (int kf = 0; kf < 4; ++kf)
      B3g[i2][kf] = *(const half8*)(wsh + H_GW3 + ((w * 4 + i2) * 16 + ln16) * 128 + kf * 32 + koff);
  {  // fW3 tile w for waves 0-3
    int cw = (w < 4 ? w : 0);
#pragma unroll
    for (int kf = 0; kf < 4; ++kf)
      B3f[kf] = *(const half8*)(wsh + H_FW3 + (cw * 16 + ln16) * 128 + kf * 32 + koff);
  }
  __syncthreads();

  // ---- z0 = init_noise @ emb_W + emb_b ----
  if (tid < 256) {
    const int rr = tid & 3, l = tid >> 2;
    const float* pe = wsf + F_EMBT + l * 32;
    float acc = emb_b[l];
#pragma unroll
    for (int c = 0; c < 8; ++c) {
      float4 a = *(const float4*)(&hrs[rr * 144 + 4 * c]);
      float4 v = *(const float4*)(pe + 4 * c);
      acc += a.x * v.x + a.y * v.y + a.z * v.z + a.w * v.w;
    }
    zb[rr * 68 + l] = acc;
    zseg[aofs2(rr, l)] = (_Float16)acc;
  }
  __syncthreads();

  // z f32 state lives in the even P4-thread's register
  float zreg = odd ? 0.f : zb[zbofs];

  // R2 helper: threads 256-511 (waves 4-7), readout of hrs -> out[T]
  auto R2 = [&](int T) {
    const float* ph = &hrs[r2r * 144 + r2kk * 32];
    const float* pw = &rw2s[r2d * 132 + r2kk * 32];
    float acc = 0.f;
#pragma unroll
    for (int c = 0; c < 8; ++c) {
      float4 a4 = *(const float4*)(ph + 4 * c);
      float4 w4 = *(const float4*)(pw + 4 * c);
      acc += a4.x * w4.x + a4.y * w4.y + a4.z * w4.z + a4.w * w4.w;
    }
    acc += __shfl_xor(acc, 4);
    acc += __shfl_xor(acc, 8);
    if (r2kk == 0) {
      float v = acc + rb2v;
      out_full[ofull + (size_t)T * 16] = v;
      if ((T & 7) == 0) out_match[omatch + (size_t)(T >> 3) * 16] = v;
    }
  };

  float dwn = 0.f;  // dW prefetch register (wave 7, lanes 0-31)

#pragma unroll 1
  for (int i = 0; i < 511; ++i) {
    const float t_s = (float)i * DTI;

    // ---- P1: L1 (f,g) + R1 sharing z A-frags; issue dW(i+1) load ----
    {
      half8 a0 = *(const half8*)(&zseg[ra]);
      half8 a1 = *(const half8*)(&zseg[512 + ra]);
      if (w == 7 && lane < 32) {
        int ip = (i < 510) ? i + 1 : 510;
        dwn = dw_noise[(size_t)ip * 8192 + b4 * 8 + lane];
      }
      floatx4 cf = {0.f, 0.f, 0.f, 0.f}, cg = {0.f, 0.f, 0.f, 0.f}, cr = {0.f, 0.f, 0.f, 0.f};
      cf = mfma16(a0, Bf1[0], cf); cf = mfma16(a1, Bf1[1], cf);
      cg = mfma16(a0, Bg1[0], cg); cg = mfma16(a1, Bg1[1], cg);
      cr = mfma16(a0, Br1[0], cr); cr = mfma16(a1, Br1[1], cr);
      // full-wave epilogue: quad q handles row q (duplication -> reg j = row j)
      float vf = qsel(cf, quad), vg = qsel(cg, quad), vr = qsel(cr, quad);
      h1f[haddr1] = (_Float16)sp(vf + b1fv + t_s * w1fv);
      h1g[haddr1] = (_Float16)sp(vg + b1gv + t_s * w1gv);
      hrs[hrsaddr] = fmaxf(vr + rb1v, 0.f);
    }
    __syncthreads();

    // ---- P2: L2 (waves 0-3 f, 4-7 g) + R2(i) + dW stash ----
    {
      const _Float16* asrc = (w < 4) ? h1f : h1g;
      half8 a[4];
#pragma unroll
      for (int s = 0; s < 4; ++s) a[s] = *(const half8*)(&asrc[s * 512 + ra]);
      floatx4 c0 = {0.f, 0.f, 0.f, 0.f}, c1 = {0.f, 0.f, 0.f, 0.f};
#pragma unroll
      for (int s = 0; s < 4; ++s) {
        c0 = mfma16(a[s], B2[0][s], c0);
        c1 = mfma16(a[s], B2[1][s], c1);
      }
      if (w == 7 && lane < 32)
        dwS[(i + 1) & 1][lane >> 3][lane & 7] = dwn * SDT;
      if (tid >= 256) R2(i);
      _Float16* dst = (w < 4) ? h2f : h2g;
      float v0 = qsel(c0, quad), v1 = qsel(c1, quad);
      dst[haddr2A] = (_Float16)sp(v0 + b2vA);
      dst[haddr2B] = (_Float16)sp(v1 + b2vB);
    }
    __syncthreads();

    // ---- P3: L3 g (4 tiles/wave) + L3 f on waves 0-3 ----
    {
      half8 ag[4];
#pragma unroll
      for (int s = 0; s < 4; ++s) ag[s] = *(const half8*)(&h2g[s * 512 + ra]);
      floatx4 cg4[4];
#pragma unroll
      for (int i2 = 0; i2 < 4; ++i2) cg4[i2] = (floatx4){0.f, 0.f, 0.f, 0.f};
#pragma unroll
      for (int s = 0; s < 4; ++s)
#pragma unroll
        for (int i2 = 0; i2 < 4; ++i2) cg4[i2] = mfma16(ag[s], B3g[i2][s], cg4[i2]);
      floatx4 cf3 = {0.f, 0.f, 0.f, 0.f};
      if (w < 4) {
#pragma unroll
        for (int s = 0; s < 4; ++s) {
          half8 af = *(const half8*)(&h2f[s * 512 + ra]);
          cf3 = mfma16(af, B3f[s], cf3);
        }
      }
#pragma unroll
      for (int i2 = 0; i2 < 4; ++i2)
        gps[gpsbase + i2 * 16] = qsel(cg4[i2], quad);
      if (w < 4) fps[fpsaddr] = qsel(cf3, quad);
    }
    __syncthreads();

    // ---- P4: z += tanh(f)*dt + sum tanh(g)*dW (pair-split, all threads) ----
    {
      const float* dwp = &dwS[0][0][0] + 48 * (i & 1);
      float4 dv = *(const float4*)(dwp + dwofs);
      float4 g = *(const float4*)(&gps[gofs]);
      float acc = ftanh(g.x + gbv4.x) * dv.x
                + ftanh(g.y + gbv4.y) * dv.y
                + ftanh(g.z + gbv4.z) * dv.z
                + ftanh(g.w + gbv4.w) * dv.w;
      if (!odd) acc += ftanh(fps[rr4 * 80 + l4] + fbv) * DTI;
      acc += __shfl_xor(acc, 1);
      if (!odd) {
        zreg += acc;
        zseg[zwaddr] = (_Float16)zreg;
      }
    }
    __syncthreads();
  }

  // ---- final readout T=511 ----
  {
    half8 a0 = *(const half8*)(&zseg[ra]);
    half8 a1 = *(const half8*)(&zseg[512 + ra]);
    floatx4 cr = {0.f, 0.f, 0.f, 0.f};
    cr = mfma16(a0, Br1[0], cr); cr = mfma16(a1, Br1[1], cr);
    float vr = qsel(cr, quad);
    hrs[hrsaddr] = fmaxf(vr + rb1v, 0.f);
  }
  __syncthreads();
  if (tid >= 256) R2(511);
}

extern "C" void kernel_launch(void* const* d_in, const int* in_sizes, int n_in,
                              void* d_out, int out_size, void* d_ws, size_t ws_size,
                              hipStream_t stream) {
  (void)in_sizes; (void)n_in; (void)out_size; (void)ws_size;
  const float* init_noise = (const float*)d_in[0];
  const float* dw_noise   = (const float*)d_in[1];
  const float* emb_W      = (const float*)d_in[3];
  const float* emb_b      = (const float*)d_in[4];
  const float* f_W1       = (const float*)d_in[5];
  const float* f_b1       = (const float*)d_in[6];
  const float* f_W2       = (const float*)d_in[7];
  const float* f_b2       = (const float*)d_in[8];
  const float* f_W3       = (const float*)d_in[9];
  const float* f_b3       = (const float*)d_in[10];
  const float* g_W1       = (const float*)d_in[11];
  const float* g_b1       = (const float*)d_in[12];
  const float* g_W2       = (const float*)d_in[13];
  const float* g_b2       = (const float*)d_in[14];
  const float* g_W3       = (const float*)d_in[15];
  const float* g_b3       = (const float*)d_in[16];
  const float* r_W1       = (const float*)d_in[17];
  const float* r_b1       = (const float*)d_in[18];
  const float* r_W2       = (const float*)d_in[19];
  const float* r_b2       = (const float*)d_in[20];
  float* out_full = (float*)d_out;
  float* out_match = out_full + (size_t)1024 * 512 * 16;

  hipLaunchKernelGGL(prep_kernel, dim3((PREP_TOTAL + 255) / 256), dim3(256), 0, stream,
                     f_W1, g_W1, f_W2, g_W2, f_W3, g_W3, r_W1, r_W2, emb_W, d_ws);
  hipLaunchKernelGGL(sde_main, dim3(256), dim3(512), 0, stream,
                     init_noise, dw_noise, emb_b, f_b1, f_b2, f_b3,
                     g_b1, g_b2, g_b3, r_b1, r_b2, d_ws, out_full, out_match);
}

// Round 4
// 957.881 us; speedup vs baseline: 6.6395x; 1.1909x over previous
//
#include <hip/hip_runtime.h>
#include <cmath>

// ---------------------------------------------------------------------------
// Round 9. r8 post-mortem: step = ~5360 cyc but only ~900 are issue -> ~80%
// stall. Structural culprit found in source: __syncthreads() drains
// vmcnt(0), so wave 7's dw_noise HBM load (~900 cyc) and the R2 out-stores
// land on the barrier path of all 8 waves EVERY step (r8's "prefetch" was
// neutralized by the next barrier's drain).
// r9:
//  1) Raw barriers in the step loop: s_waitcnt lgkmcnt(0) + s_barrier
//     ("memory"-fenced on both sides). vmcnt deliberately NOT drained ->
//     dW loads / out stores stay in flight across barriers.
//  2) R2 readout as MFMA on wave 4 only: hrs -> f16 lane-linear buffer,
//     rW2 -> f16 B-frags sharing the register slot with fW3 (w<4 union).
//     Replaces 4 waves x (32 fma + 16 ds_read + shfl) with 4 MFMA + one
//     full-wave coalesced store. Frees rw2s LDS (8.4KB) + its init.
// Everything else = r8 (quad-duplication, reg constants, pair-split P4,
// dW double-buffer, 4 phases/step).
// ---------------------------------------------------------------------------

typedef _Float16 half8 __attribute__((ext_vector_type(8)));
typedef float floatx4 __attribute__((ext_vector_type(4)));

// ws layout: f16 region (offsets in _Float16 units)
#define H_FW1 0        // [128][64]
#define H_GW1 8192     // [128][64]
#define H_FW2 16384    // [128][128]
#define H_GW2 32768    // [128][128]
#define H_FW3 49152    // [64][128]
#define H_GW3 57344    // [512][128]
#define H_RW1 122880   // [128][64]
#define H_RW2 131072   // [16][128]  (f16 readout weights, transposed)
#define H_TOTAL 133120
// f32 region (offsets in float units from ws base; starts right after f16)
#define F_EMBT 66560             // [64][32]
#define F_W1R0F (F_EMBT + 2048)  // [128]
#define F_W1R0G (F_W1R0F + 128)  // [128]
#define F_CNT 2304
#define PREP_TOTAL (H_TOTAL + F_CNT)

__global__ void prep_kernel(const float* __restrict__ fW1, const float* __restrict__ gW1,
                            const float* __restrict__ fW2, const float* __restrict__ gW2,
                            const float* __restrict__ fW3, const float* __restrict__ gW3,
                            const float* __restrict__ rW1, const float* __restrict__ rW2,
                            const float* __restrict__ embW, void* __restrict__ ws) {
  int idx = blockIdx.x * blockDim.x + threadIdx.x;
  if (idx >= PREP_TOTAL) return;
  if (idx < H_TOTAL) {
    float v;
    if (idx < H_GW1) {
      int t = idx; int c = t >> 6, k = t & 63; v = fW1[(k + 1) * 128 + c];
    } else if (idx < H_FW2) {
      int t = idx - H_GW1; int c = t >> 6, k = t & 63; v = gW1[(k + 1) * 128 + c];
    } else if (idx < H_GW2) {
      int t = idx - H_FW2; int c = t >> 7, k = t & 127; v = fW2[k * 128 + c];
    } else if (idx < H_FW3) {
      int t = idx - H_GW2; int c = t >> 7, k = t & 127; v = gW2[k * 128 + c];
    } else if (idx < H_GW3) {
      int t = idx - H_FW3; int c = t >> 7, k = t & 127; v = fW3[k * 64 + c];
    } else if (idx < H_RW1) {
      int t = idx - H_GW3; int c = t >> 7, k = t & 127; v = gW3[k * 512 + c];
    } else if (idx < H_RW2) {
      int t = idx - H_RW1; int c = t >> 6, k = t & 63; v = rW1[k * 128 + c];
    } else {
      int t = idx - H_RW2; int c = t >> 7, k = t & 127; v = rW2[k * 16 + c];
    }
    ((_Float16*)ws)[idx] = (_Float16)v;
  } else {
    int f = idx - H_TOTAL;
    float v;
    if (f < 2048) {
      int c = f >> 5, k = f & 31; v = embW[k * 64 + c];
      ((float*)ws)[F_EMBT + f] = v;
    } else if (f < 2176) {
      ((float*)ws)[F_W1R0F + (f - 2048)] = fW1[f - 2048];
    } else {
      ((float*)ws)[F_W1R0G + (f - 2176)] = gW1[f - 2176];
    }
  }
}

__device__ __forceinline__ float sp(float x) { return __logf(1.f + __expf(x)); }

// clamp-free tanh: exp(2x)->inf gives 1-0=1; exp(2x)->0 gives 1-2=-1.
__device__ __forceinline__ float ftanh(float x) {
  float e = __expf(2.f * x);
  return 1.f - __fdividef(2.f, e + 1.f);
}

__device__ __forceinline__ floatx4 mfma16(half8 a, half8 b, floatx4 c) {
  return __builtin_amdgcn_mfma_f32_16x16x32_f16(a, b, c, 0, 0, 0);
}

// lane-linear A-layout with sub-k bank shift.
// element (m,k): seg(k>>5)*512 + subk*128 + (subk&1)*32 + m*8 + (k&7)
__device__ __forceinline__ int aofs2(int m, int k) {
  int subk = (k >> 3) & 3;
  return ((k >> 5) << 9) + (subk << 7) + ((subk & 1) << 5) + (m << 3) + (k & 7);
}

// select element `quad` of a floatx4 with static indices; with duplicated-A
// reads, c[quad] at any quad-group holds real row `quad` (row 5q mod 4 = q).
__device__ __forceinline__ float qsel(floatx4 c, int quad) {
  float v01 = (quad & 1) ? c[1] : c[0];
  float v23 = (quad & 1) ? c[3] : c[2];
  return (quad & 2) ? v23 : v01;
}

// Raw phase barrier: LDS-ordering only; vmcnt left in flight on purpose.
#define BAR()                                                    \
  do {                                                           \
    asm volatile("s_waitcnt lgkmcnt(0)" ::: "memory");           \
    __builtin_amdgcn_s_barrier();                                \
    asm volatile("" ::: "memory");                               \
  } while (0)

__global__ __launch_bounds__(512, 2)
void sde_main(const float* __restrict__ init_noise, const float* __restrict__ dw_noise,
              const float* __restrict__ emb_b,
              const float* __restrict__ f_b1, const float* __restrict__ f_b2,
              const float* __restrict__ f_b3, const float* __restrict__ g_b1,
              const float* __restrict__ g_b2, const float* __restrict__ g_b3,
              const float* __restrict__ r_b1, const float* __restrict__ r_b2,
              const void* __restrict__ ws, float* __restrict__ out_full,
              float* __restrict__ out_match) {
  // lane-linear f16 activation buffers (rows 0-3 real, duplicated reads)
  __shared__ __align__(16) _Float16 zseg[1024];                 // z, K=64
  __shared__ __align__(16) _Float16 h1f[2048], h1g[2048];       // K=128
  __shared__ __align__(16) _Float16 h2f[2048], h2g[2048];
  __shared__ __align__(16) _Float16 hrsg[2048];                 // readout hidden (f16)
  // f32 scratch
  __shared__ __align__(16) float fps[4 * 80];     // f3 pre-act
  __shared__ __align__(16) float gps[4 * 532];    // g3 pre-act (+init staging)
  __shared__ __align__(16) float zb[4 * 68];      // z state f32 (init staging)
  __shared__ __align__(16) float dwS[2][4][12];   // double-buffered dW

  const int tid = threadIdx.x;
  const int w = tid >> 6;          // wave 0..7
  const int lane = tid & 63;
  const int ln16 = lane & 15;
  const int quad = lane >> 4;
  const int koff = quad * 8;
  const int wm = w & 3;
  const int b4 = blockIdx.x << 2;
  const _Float16* wsh = (const _Float16*)ws;
  const float* wsf = (const float*)ws;

  const float DTI = 1.0f / 511.0f;
  const float SDT = sqrtf(DTI);

  // ---- step-invariant per-lane constants (registers) ----
  const int col1 = w * 16 + ln16;                 // P1/R1 column
  const float b1fv = f_b1[col1], b1gv = g_b1[col1];
  const float w1fv = wsf[F_W1R0F + col1], w1gv = wsf[F_W1R0G + col1];
  const float rb1v = r_b1[col1];
  const int colA = wm * 32 + ln16, colB = colA + 16;  // P2 columns
  const float* bsrc2 = (w < 4) ? f_b2 : g_b2;
  const float b2vA = bsrc2[colA], b2vB = bsrc2[colB];
  // duplicated A-read offset (within a 512-f16 seg)
  const int ra = ((lane >> 4) << 7) + (((lane >> 4) & 1) << 5) + ((lane & 3) << 3);
  // write addresses
  const int haddr1 = aofs2(quad, col1);
  const int haddr2A = aofs2(quad, colA), haddr2B = aofs2(quad, colB);
  const int gpsbase = quad * 532 + w * 64 + ln16; // + i2*16
  const int fpsaddr = quad * 80 + (w & 3) * 16 + ln16;
  // P4 (pair-split over all 512 threads)
  const int odd = tid & 1, hh = tid >> 1;
  const int rr4 = hh & 3, l4 = hh >> 2, o4 = odd * 4;
  const int gofs = rr4 * 532 + l4 * 8 + o4;
  const int dwofs = rr4 * 12 + o4;                // + 48*(i&1)
  const int zwaddr = aofs2(rr4, l4);
  const int zbofs = rr4 * 68 + l4;
  const float fbv = f_b3[l4];
  const float4 gbv4 = *(const float4*)(&g_b3[l4 * 8 + o4]);
  // R2-MFMA constants (wave 4): lane (quad,ln16) stores row quad, dim ln16
  const float rb2v = r_b2[ln16];
  const size_t ofull4 = ((size_t)(b4 + quad) * 512) * 16 + ln16;
  const size_t omatch4 = ((size_t)(b4 + quad) * 64) * 16 + ln16;

  // ---- init: stage init_noise into gps (f32 scratch, free pre-loop) ----
  if (tid < 128) gps[(tid >> 5) * 532 + (tid & 31)] = init_noise[b4 * 32 + tid];
  if (w == 7 && lane < 32)
    dwS[0][lane >> 3][lane & 7] = dw_noise[b4 * 8 + lane] * SDT;

  // ---- persistent B-fragments (VGPR-resident for all 511 steps) ----
  // U3: waves 0-3 -> fW3 tile w (used in P3); waves 4-7 -> rW2 tile (P2/R2)
  half8 Bf1[2], Bg1[2], Br1[2], B2[2][4], B3g[4][4], U3[4];
#pragma unroll
  for (int kf = 0; kf < 2; ++kf) {
    Bf1[kf] = *(const half8*)(wsh + H_FW1 + col1 * 64 + kf * 32 + koff);
    Bg1[kf] = *(const half8*)(wsh + H_GW1 + col1 * 64 + kf * 32 + koff);
    Br1[kf] = *(const half8*)(wsh + H_RW1 + col1 * 64 + kf * 32 + koff);
  }
  const _Float16* w2b = wsh + (w < 4 ? H_FW2 : H_GW2);
#pragma unroll
  for (int i2 = 0; i2 < 2; ++i2)
#pragma unroll
    for (int kf = 0; kf < 4; ++kf)
      B2[i2][kf] = *(const half8*)(w2b + ((wm * 2 + i2) * 16 + ln16) * 128 + kf * 32 + koff);
#pragma unroll
  for (int i2 = 0; i2 < 4; ++i2)
#pragma unroll
    for (int kf = 0; kf < 4; ++kf)
      B3g[i2][kf] = *(const half8*)(wsh + H_GW3 + ((w * 4 + i2) * 16 + ln16) * 128 + kf * 32 + koff);
  {
    const _Float16* u3b = (w < 4) ? (wsh + H_FW3 + (wm * 16 + ln16) * 128)
                                  : (wsh + H_RW2 + ln16 * 128);
#pragma unroll
    for (int kf = 0; kf < 4; ++kf)
      U3[kf] = *(const half8*)(u3b + kf * 32 + koff);
  }
  __syncthreads();

  // ---- z0 = init_noise @ emb_W + emb_b ----
  if (tid < 256) {
    const int rr = tid & 3, l = tid >> 2;
    const float* pe = wsf + F_EMBT + l * 32;
    float acc = emb_b[l];
#pragma unroll
    for (int c = 0; c < 8; ++c) {
      float4 a = *(const float4*)(&gps[rr * 532 + 4 * c]);
      float4 v = *(const float4*)(pe + 4 * c);
      acc += a.x * v.x + a.y * v.y + a.z * v.z + a.w * v.w;
    }
    zb[rr * 68 + l] = acc;
    zseg[aofs2(rr, l)] = (_Float16)acc;
  }
  __syncthreads();

  // z f32 state lives in the even P4-thread's register
  float zreg = odd ? 0.f : zb[zbofs];

  float dwn = 0.f;  // dW prefetch register (wave 7, lanes 0-31)

#pragma unroll 1
  for (int i = 0; i < 511; ++i) {
    const float t_s = (float)i * DTI;

    // ---- P1: L1 (f,g) + R1 sharing z A-frags; issue dW(i+1) load ----
    {
      half8 a0 = *(const half8*)(&zseg[ra]);
      half8 a1 = *(const half8*)(&zseg[512 + ra]);
      if (w == 7 && lane < 32) {
        int ip = (i < 510) ? i + 1 : 510;
        dwn = dw_noise[(size_t)ip * 8192 + b4 * 8 + lane];
      }
      floatx4 cf = {0.f, 0.f, 0.f, 0.f}, cg = {0.f, 0.f, 0.f, 0.f}, cr = {0.f, 0.f, 0.f, 0.f};
      cf = mfma16(a0, Bf1[0], cf); cf = mfma16(a1, Bf1[1], cf);
      cg = mfma16(a0, Bg1[0], cg); cg = mfma16(a1, Bg1[1], cg);
      cr = mfma16(a0, Br1[0], cr); cr = mfma16(a1, Br1[1], cr);
      float vf = qsel(cf, quad), vg = qsel(cg, quad), vr = qsel(cr, quad);
      h1f[haddr1] = (_Float16)sp(vf + b1fv + t_s * w1fv);
      h1g[haddr1] = (_Float16)sp(vg + b1gv + t_s * w1gv);
      hrsg[haddr1] = (_Float16)fmaxf(vr + rb1v, 0.f);
    }
    BAR();

    // ---- P2: L2 (waves 0-3 f, 4-7 g) + R2-MFMA (wave 4) + dW stash ----
    {
      const _Float16* asrc = (w < 4) ? h1f : h1g;
      half8 a[4];
#pragma unroll
      for (int s = 0; s < 4; ++s) a[s] = *(const half8*)(&asrc[s * 512 + ra]);
      floatx4 c0 = {0.f, 0.f, 0.f, 0.f}, c1 = {0.f, 0.f, 0.f, 0.f};
#pragma unroll
      for (int s = 0; s < 4; ++s) {
        c0 = mfma16(a[s], B2[0][s], c0);
        c1 = mfma16(a[s], B2[1][s], c1);
      }
      if (w == 4) {
        half8 hr[4];
#pragma unroll
        for (int s = 0; s < 4; ++s) hr[s] = *(const half8*)(&hrsg[s * 512 + ra]);
        floatx4 co = {0.f, 0.f, 0.f, 0.f};
#pragma unroll
        for (int s = 0; s < 4; ++s) co = mfma16(hr[s], U3[s], co);
        float v = qsel(co, quad) + rb2v;
        out_full[ofull4 + (size_t)i * 16] = v;
        if ((i & 7) == 0) out_match[omatch4 + (size_t)(i >> 3) * 16] = v;
      }
      if (w == 7 && lane < 32)
        dwS[(i + 1) & 1][lane >> 3][lane & 7] = dwn * SDT;
      _Float16* dst = (w < 4) ? h2f : h2g;
      float v0 = qsel(c0, quad), v1 = qsel(c1, quad);
      dst[haddr2A] = (_Float16)sp(v0 + b2vA);
      dst[haddr2B] = (_Float16)sp(v1 + b2vB);
    }
    BAR();

    // ---- P3: L3 g (4 tiles/wave) + L3 f on waves 0-3 (U3 = fW3) ----
    {
      half8 ag[4];
#pragma unroll
      for (int s = 0; s < 4; ++s) ag[s] = *(const half8*)(&h2g[s * 512 + ra]);
      floatx4 cg4[4];
#pragma unroll
      for (int i2 = 0; i2 < 4; ++i2) cg4[i2] = (floatx4){0.f, 0.f, 0.f, 0.f};
#pragma unroll
      for (int s = 0; s < 4; ++s)
#pragma unroll
        for (int i2 = 0; i2 < 4; ++i2) cg4[i2] = mfma16(ag[s], B3g[i2][s], cg4[i2]);
      floatx4 cf3 = {0.f, 0.f, 0.f, 0.f};
      if (w < 4) {
#pragma unroll
        for (int s = 0; s < 4; ++s) {
          half8 af = *(const half8*)(&h2f[s * 512 + ra]);
          cf3 = mfma16(af, U3[s], cf3);
        }
      }
#pragma unroll
      for (int i2 = 0; i2 < 4; ++i2)
        gps[gpsbase + i2 * 16] = qsel(cg4[i2], quad);
      if (w < 4) fps[fpsaddr] = qsel(cf3, quad);
    }
    BAR();

    // ---- P4: z += tanh(f)*dt + sum tanh(g)*dW (pair-split, all threads) ----
    {
      const float* dwp = &dwS[0][0][0] + 48 * (i & 1);
      float4 dv = *(const float4*)(dwp + dwofs);
      float4 g = *(const float4*)(&gps[gofs]);
      float acc = ftanh(g.x + gbv4.x) * dv.x
                + ftanh(g.y + gbv4.y) * dv.y
                + ftanh(g.z + gbv4.z) * dv.z
                + ftanh(g.w + gbv4.w) * dv.w;
      if (!odd) acc += ftanh(fps[rr4 * 80 + l4] + fbv) * DTI;
      acc += __shfl_xor(acc, 1);
      if (!odd) {
        zreg += acc;
        zseg[zwaddr] = (_Float16)zreg;
      }
    }
    BAR();
  }

  // ---- final readout T=511 ----
  {
    half8 a0 = *(const half8*)(&zseg[ra]);
    half8 a1 = *(const half8*)(&zseg[512 + ra]);
    floatx4 cr = {0.f, 0.f, 0.f, 0.f};
    cr = mfma16(a0, Br1[0], cr); cr = mfma16(a1, Br1[1], cr);
    float vr = qsel(cr, quad);
    hrsg[haddr1] = (_Float16)fmaxf(vr + rb1v, 0.f);
  }
  BAR();
  if (w == 4) {
    half8 hr[4];
#pragma unroll
    for (int s = 0; s < 4; ++s) hr[s] = *(const half8*)(&hrsg[s * 512 + ra]);
    floatx4 co = {0.f, 0.f, 0.f, 0.f};
#pragma unroll
    for (int s = 0; s < 4; ++s) co = mfma16(hr[s], U3[s], co);
    float v = qsel(co, quad) + rb2v;
    out_full[ofull4 + (size_t)511 * 16] = v;
  }
}

extern "C" void kernel_launch(void* const* d_in, const int* in_sizes, int n_in,
                              void* d_out, int out_size, void* d_ws, size_t ws_size,
                              hipStream_t stream) {
  (void)in_sizes; (void)n_in; (void)out_size; (void)ws_size;
  const float* init_noise = (const float*)d_in[0];
  const float* dw_noise   = (const float*)d_in[1];
  const float* emb_W      = (const float*)d_in[3];
  const float* emb_b      = (const float*)d_in[4];
  const float* f_W1       = (const float*)d_in[5];
  const float* f_b1       = (const float*)d_in[6];
  const float* f_W2       = (const float*)d_in[7];
  const float* f_b2       = (const float*)d_in[8];
  const float* f_W3       = (const float*)d_in[9];
  const float* f_b3       = (const float*)d_in[10];
  const float* g_W1       = (const float*)d_in[11];
  const float* g_b1       = (const float*)d_in[12];
  const float* g_W2       = (const float*)d_in[13];
  const float* g_b2       = (const float*)d_in[14];
  const float* g_W3       = (const float*)d_in[15];
  const float* g_b3       = (const float*)d_in[16];
  const float* r_W1       = (const float*)d_in[17];
  const float* r_b1       = (const float*)d_in[18];
  const float* r_W2       = (const float*)d_in[19];
  const float* r_b2       = (const float*)d_in[20];
  float* out_full = (float*)d_out;
  float* out_match = out_full + (size_t)1024 * 512 * 16;

  hipLaunchKernelGGL(prep_kernel, dim3((PREP_TOTAL + 255) / 256), dim3(256), 0, stream,
                     f_W1, g_W1, f_W2, g_W2, f_W3, g_W3, r_W1, r_W2, emb_W, d_ws);
  hipLaunchKernelGGL(sde_main, dim3(256), dim3(512), 0, stream,
                     init_noise, dw_noise, emb_b, f_b1, f_b2, f_b3,
                     g_b1, g_b2, g_b3, r_b1, r_b2, d_ws, out_full, out_match);
}

// Round 5
// 948.481 us; speedup vs baseline: 6.7053x; 1.0099x over previous
//
#include <hip/hip_runtime.h>
#include <cmath>

// ---------------------------------------------------------------------------
// Round 10. r9 = 936us. Per-step critical path = 4 phases x (LDS-read lat ->
// MFMA -> transcendental epilogue -> LDS-write lat -> lgkm+barrier). P4
// exists only to redistribute g3/f3 pre-acts through LDS (gps/fps). But P3's
// output layout is wave-locally reducible: for fixed i2, lanes of a quad-group
// hold g3[quad][col] with n=ln16&7, l=w*8+i2*2+(ln16>>3) -> the 8-term
// noise contraction is 3 shfl_xor per i2 within the producing wave.
// r10: merge P4 into P3.
//  - all 8 waves compute fW3 tile (w>>1) (duplicated, +4 MFMA/wave); f-term
//    fetched by owner lane via 1 shuffle.
//  - tanh(g)+dW weighting per lane, butterfly allreduce xor{1,2,4}, z state
//    f32 in owner-lane register, single ds_write_b16 of z' to zseg.
//  - rW2 gets dedicated frags R2W (U3 union freed); gps/fps LDS deleted.
//  - 3 barriers/step, one LDS round-trip removed from the critical path.
// Everything else = r9 (raw lgkm-only barriers, R2-MFMA on wave 4, quad-dup
// A-reads, reg-resident weights, dW double-buffer prefetch).
// ---------------------------------------------------------------------------

typedef _Float16 half8 __attribute__((ext_vector_type(8)));
typedef float floatx4 __attribute__((ext_vector_type(4)));

// ws layout: f16 region (offsets in _Float16 units)
#define H_FW1 0        // [128][64]
#define H_GW1 8192     // [128][64]
#define H_FW2 16384    // [128][128]
#define H_GW2 32768    // [128][128]
#define H_FW3 49152    // [64][128]
#define H_GW3 57344    // [512][128]
#define H_RW1 122880   // [128][64]
#define H_RW2 131072   // [16][128]  (f16 readout weights, transposed)
#define H_TOTAL 133120
// f32 region (offsets in float units from ws base; starts right after f16)
#define F_EMBT 66560             // [64][32]
#define F_W1R0F (F_EMBT + 2048)  // [128]
#define F_W1R0G (F_W1R0F + 128)  // [128]
#define F_CNT 2304
#define PREP_TOTAL (H_TOTAL + F_CNT)

__global__ void prep_kernel(const float* __restrict__ fW1, const float* __restrict__ gW1,
                            const float* __restrict__ fW2, const float* __restrict__ gW2,
                            const float* __restrict__ fW3, const float* __restrict__ gW3,
                            const float* __restrict__ rW1, const float* __restrict__ rW2,
                            const float* __restrict__ embW, void* __restrict__ ws) {
  int idx = blockIdx.x * blockDim.x + threadIdx.x;
  if (idx >= PREP_TOTAL) return;
  if (idx < H_TOTAL) {
    float v;
    if (idx < H_GW1) {
      int t = idx; int c = t >> 6, k = t & 63; v = fW1[(k + 1) * 128 + c];
    } else if (idx < H_FW2) {
      int t = idx - H_GW1; int c = t >> 6, k = t & 63; v = gW1[(k + 1) * 128 + c];
    } else if (idx < H_GW2) {
      int t = idx - H_FW2; int c = t >> 7, k = t & 127; v = fW2[k * 128 + c];
    } else if (idx < H_FW3) {
      int t = idx - H_GW2; int c = t >> 7, k = t & 127; v = gW2[k * 128 + c];
    } else if (idx < H_GW3) {
      int t = idx - H_FW3; int c = t >> 7, k = t & 127; v = fW3[k * 64 + c];
    } else if (idx < H_RW1) {
      int t = idx - H_GW3; int c = t >> 7, k = t & 127; v = gW3[k * 512 + c];
    } else if (idx < H_RW2) {
      int t = idx - H_RW1; int c = t >> 6, k = t & 63; v = rW1[k * 128 + c];
    } else {
      int t = idx - H_RW2; int c = t >> 7, k = t & 127; v = rW2[k * 16 + c];
    }
    ((_Float16*)ws)[idx] = (_Float16)v;
  } else {
    int f = idx - H_TOTAL;
    float v;
    if (f < 2048) {
      int c = f >> 5, k = f & 31; v = embW[k * 64 + c];
      ((float*)ws)[F_EMBT + f] = v;
    } else if (f < 2176) {
      ((float*)ws)[F_W1R0F + (f - 2048)] = fW1[f - 2048];
    } else {
      ((float*)ws)[F_W1R0G + (f - 2176)] = gW1[f - 2176];
    }
  }
}

__device__ __forceinline__ float sp(float x) { return __logf(1.f + __expf(x)); }

// clamp-free tanh: exp(2x)->inf gives 1-0=1; exp(2x)->0 gives 1-2=-1.
__device__ __forceinline__ float ftanh(float x) {
  float e = __expf(2.f * x);
  return 1.f - __fdividef(2.f, e + 1.f);
}

__device__ __forceinline__ floatx4 mfma16(half8 a, half8 b, floatx4 c) {
  return __builtin_amdgcn_mfma_f32_16x16x32_f16(a, b, c, 0, 0, 0);
}

// lane-linear A-layout with sub-k bank shift.
// element (m,k): seg(k>>5)*512 + subk*128 + (subk&1)*32 + m*8 + (k&7)
__device__ __forceinline__ int aofs2(int m, int k) {
  int subk = (k >> 3) & 3;
  return ((k >> 5) << 9) + (subk << 7) + ((subk & 1) << 5) + (m << 3) + (k & 7);
}

// select element `quad` of a floatx4 with static indices (rule #20 safe)
__device__ __forceinline__ float qsel(floatx4 c, int quad) {
  float v01 = (quad & 1) ? c[1] : c[0];
  float v23 = (quad & 1) ? c[3] : c[2];
  return (quad & 2) ? v23 : v01;
}

// select element `s` of 4 scalars (rule #20 safe)
__device__ __forceinline__ float sel4(float v0, float v1, float v2, float v3, int s) {
  float a = (s & 1) ? v1 : v0;
  float b = (s & 1) ? v3 : v2;
  return (s & 2) ? b : a;
}

// Raw phase barrier: LDS-ordering only; vmcnt left in flight on purpose.
#define BAR()                                                    \
  do {                                                           \
    asm volatile("s_waitcnt lgkmcnt(0)" ::: "memory");           \
    __builtin_amdgcn_s_barrier();                                \
    asm volatile("" ::: "memory");                               \
  } while (0)

__global__ __launch_bounds__(512, 2)
void sde_main(const float* __restrict__ init_noise, const float* __restrict__ dw_noise,
              const float* __restrict__ emb_b,
              const float* __restrict__ f_b1, const float* __restrict__ f_b2,
              const float* __restrict__ f_b3, const float* __restrict__ g_b1,
              const float* __restrict__ g_b2, const float* __restrict__ g_b3,
              const float* __restrict__ r_b1, const float* __restrict__ r_b2,
              const void* __restrict__ ws, float* __restrict__ out_full,
              float* __restrict__ out_match) {
  // lane-linear f16 activation buffers (rows 0-3 real, duplicated reads)
  __shared__ __align__(16) _Float16 zseg[1024];                 // z, K=64
  __shared__ __align__(16) _Float16 h1f[2048], h1g[2048];       // K=128
  __shared__ __align__(16) _Float16 h2f[2048], h2g[2048];
  __shared__ __align__(16) _Float16 hrsg[2048];                 // readout hidden (f16)
  // f32 scratch
  __shared__ __align__(16) float zb[4 * 68];      // z0 staging
  __shared__ __align__(16) float dwS[2][4][12];   // double-buffered dW
  __shared__ __align__(16) float stg[4 * 36];     // init_noise staging

  const int tid = threadIdx.x;
  const int w = tid >> 6;          // wave 0..7
  const int lane = tid & 63;
  const int ln16 = lane & 15;
  const int quad = lane >> 4;
  const int koff = quad * 8;
  const int wm = w & 3;
  const int b4 = blockIdx.x << 2;
  const _Float16* wsh = (const _Float16*)ws;
  const float* wsf = (const float*)ws;

  const float DTI = 1.0f / 511.0f;
  const float SDT = sqrtf(DTI);

  // ---- step-invariant per-lane constants (registers) ----
  const int col1 = w * 16 + ln16;                 // P1/R1 column
  const float b1fv = f_b1[col1], b1gv = g_b1[col1];
  const float w1fv = wsf[F_W1R0F + col1], w1gv = wsf[F_W1R0G + col1];
  const float rb1v = r_b1[col1];
  const int colA = wm * 32 + ln16, colB = colA + 16;  // P2 columns
  const float* bsrc2 = (w < 4) ? f_b2 : g_b2;
  const float b2vA = bsrc2[colA], b2vB = bsrc2[colB];
  // duplicated A-read offset (within a 512-f16 seg)
  const int ra = ((lane >> 4) << 7) + (((lane >> 4) & 1) << 5) + ((lane & 3) << 3);
  // write addresses
  const int haddr1 = aofs2(quad, col1);
  const int haddr2A = aofs2(quad, colA), haddr2B = aofs2(quad, colB);
  // P3 z-update constants
  const int n8 = ln16 & 7;                   // noise index for this lane
  const int hlf = ln16 >> 3;                 // which half of the 16-group
  const bool writer = ((n8 & 1) == hlf);     // owner of z(quad, lstar)
  const int lstar = (w << 3) + n8;           // owned z column
  const int i2sel = n8 >> 1;                 // butterfly sum to use
  const int fsrc = quad * 16 + ((w & 1) << 3) + n8;  // lane holding f-term
  const int zwaddr = aofs2(quad, lstar);
  const int fcol = ((w >> 1) << 4) + ln16;   // this lane's fW3 column
  const float fb3v = f_b3[fcol];
  const float gb0 = g_b3[w * 64 + 0 * 16 + ln16];
  const float gb1 = g_b3[w * 64 + 1 * 16 + ln16];
  const float gb2 = g_b3[w * 64 + 2 * 16 + ln16];
  const float gb3v = g_b3[w * 64 + 3 * 16 + ln16];
  // R2-MFMA constants (wave 4): lane (quad,ln16) stores row quad, dim ln16
  const float rb2v = r_b2[ln16];
  const size_t ofull4 = ((size_t)(b4 + quad) * 512) * 16 + ln16;
  const size_t omatch4 = ((size_t)(b4 + quad) * 64) * 16 + ln16;

  // ---- init: stage init_noise (f32) ----
  if (tid < 128) stg[(tid >> 5) * 36 + (tid & 31)] = init_noise[b4 * 32 + tid];
  if (w == 7 && lane < 32)
    dwS[0][lane >> 3][lane & 7] = dw_noise[b4 * 8 + lane] * SDT;

  // ---- persistent B-fragments (VGPR/AGPR-resident for all 511 steps) ----
  // U3: fW3 tile (w>>1) on ALL waves (P3); R2W: rW2 tile (wave 4, P2/final)
  half8 Bf1[2], Bg1[2], Br1[2], B2[2][4], B3g[4][4], U3[4], R2W[4];
#pragma unroll
  for (int kf = 0; kf < 2; ++kf) {
    Bf1[kf] = *(const half8*)(wsh + H_FW1 + col1 * 64 + kf * 32 + koff);
    Bg1[kf] = *(const half8*)(wsh + H_GW1 + col1 * 64 + kf * 32 + koff);
    Br1[kf] = *(const half8*)(wsh + H_RW1 + col1 * 64 + kf * 32 + koff);
  }
  const _Float16* w2b = wsh + (w < 4 ? H_FW2 : H_GW2);
#pragma unroll
  for (int i2 = 0; i2 < 2; ++i2)
#pragma unroll
    for (int kf = 0; kf < 4; ++kf)
      B2[i2][kf] = *(const half8*)(w2b + ((wm * 2 + i2) * 16 + ln16) * 128 + kf * 32 + koff);
#pragma unroll
  for (int i2 = 0; i2 < 4; ++i2)
#pragma unroll
    for (int kf = 0; kf < 4; ++kf)
      B3g[i2][kf] = *(const half8*)(wsh + H_GW3 + ((w * 4 + i2) * 16 + ln16) * 128 + kf * 32 + koff);
#pragma unroll
  for (int kf = 0; kf < 4; ++kf) {
    U3[kf] = *(const half8*)(wsh + H_FW3 + fcol * 128 + kf * 32 + koff);
    R2W[kf] = *(const half8*)(wsh + H_RW2 + ln16 * 128 + kf * 32 + koff);
  }
  __syncthreads();

  // ---- z0 = init_noise @ emb_W + emb_b ----
  if (tid < 256) {
    const int rr = tid & 3, l = tid >> 2;
    const float* pe = wsf + F_EMBT + l * 32;
    float acc = emb_b[l];
#pragma unroll
    for (int c = 0; c < 8; ++c) {
      float4 a = *(const float4*)(&stg[rr * 36 + 4 * c]);
      float4 v = *(const float4*)(pe + 4 * c);
      acc += a.x * v.x + a.y * v.y + a.z * v.z + a.w * v.w;
    }
    zb[rr * 68 + l] = acc;
    zseg[aofs2(rr, l)] = (_Float16)acc;
  }
  __syncthreads();

  // z f32 state lives in the owner lane's register
  float zreg = writer ? zb[quad * 68 + lstar] : 0.f;

  float dwn = 0.f;  // dW prefetch register (wave 7, lanes 0-31)

#pragma unroll 1
  for (int i = 0; i < 511; ++i) {
    const float t_s = (float)i * DTI;

    // ---- P1: L1 (f,g) + R1 sharing z A-frags; issue dW(i+1) load ----
    {
      half8 a0 = *(const half8*)(&zseg[ra]);
      half8 a1 = *(const half8*)(&zseg[512 + ra]);
      if (w == 7 && lane < 32) {
        int ip = (i < 510) ? i + 1 : 510;
        dwn = dw_noise[(size_t)ip * 8192 + b4 * 8 + lane];
      }
      floatx4 cf = {0.f, 0.f, 0.f, 0.f}, cg = {0.f, 0.f, 0.f, 0.f}, cr = {0.f, 0.f, 0.f, 0.f};
      cf = mfma16(a0, Bf1[0], cf); cf = mfma16(a1, Bf1[1], cf);
      cg = mfma16(a0, Bg1[0], cg); cg = mfma16(a1, Bg1[1], cg);
      cr = mfma16(a0, Br1[0], cr); cr = mfma16(a1, Br1[1], cr);
      float vf = qsel(cf, quad), vg = qsel(cg, quad), vr = qsel(cr, quad);
      h1f[haddr1] = (_Float16)sp(vf + b1fv + t_s * w1fv);
      h1g[haddr1] = (_Float16)sp(vg + b1gv + t_s * w1gv);
      hrsg[haddr1] = (_Float16)fmaxf(vr + rb1v, 0.f);
    }
    BAR();

    // ---- P2: L2 (waves 0-3 f, 4-7 g) + R2-MFMA (wave 4) + dW stash ----
    {
      const _Float16* asrc = (w < 4) ? h1f : h1g;
      half8 a[4];
#pragma unroll
      for (int s = 0; s < 4; ++s) a[s] = *(const half8*)(&asrc[s * 512 + ra]);
      floatx4 c0 = {0.f, 0.f, 0.f, 0.f}, c1 = {0.f, 0.f, 0.f, 0.f};
#pragma unroll
      for (int s = 0; s < 4; ++s) {
        c0 = mfma16(a[s], B2[0][s], c0);
        c1 = mfma16(a[s], B2[1][s], c1);
      }
      if (w == 4) {
        half8 hr[4];
#pragma unroll
        for (int s = 0; s < 4; ++s) hr[s] = *(const half8*)(&hrsg[s * 512 + ra]);
        floatx4 co = {0.f, 0.f, 0.f, 0.f};
#pragma unroll
        for (int s = 0; s < 4; ++s) co = mfma16(hr[s], R2W[s], co);
        float v = qsel(co, quad) + rb2v;
        out_full[ofull4 + (size_t)i * 16] = v;
        if ((i & 7) == 0) out_match[omatch4 + (size_t)(i >> 3) * 16] = v;
      }
      if (w == 7 && lane < 32)
        dwS[(i + 1) & 1][lane >> 3][lane & 7] = dwn * SDT;
      _Float16* dst = (w < 4) ? h2f : h2g;
      float v0 = qsel(c0, quad), v1 = qsel(c1, quad);
      dst[haddr2A] = (_Float16)sp(v0 + b2vA);
      dst[haddr2B] = (_Float16)sp(v1 + b2vB);
    }
    BAR();

    // ---- P3: L3 g (4 tiles) + L3 f (dup tile w>>1) + fused z-update ----
    {
      half8 ag[4];
#pragma unroll
      for (int s = 0; s < 4; ++s) ag[s] = *(const half8*)(&h2g[s * 512 + ra]);
      floatx4 cg4[4];
#pragma unroll
      for (int i2 = 0; i2 < 4; ++i2) cg4[i2] = (floatx4){0.f, 0.f, 0.f, 0.f};
#pragma unroll
      for (int s = 0; s < 4; ++s)
#pragma unroll
        for (int i2 = 0; i2 < 4; ++i2) cg4[i2] = mfma16(ag[s], B3g[i2][s], cg4[i2]);
      floatx4 cf3 = {0.f, 0.f, 0.f, 0.f};
#pragma unroll
      for (int s = 0; s < 4; ++s) {
        half8 af = *(const half8*)(&h2f[s * 512 + ra]);
        cf3 = mfma16(af, U3[s], cf3);
      }
      // per-lane noise weight dW[quad][n8] (current step's buffer)
      float dwv = dwS[i & 1][quad][n8];
      // f-term (each lane computes its own fW3-column value)
      float ft = ftanh(qsel(cf3, quad) + fb3v) * DTI;
      // weighted g-terms, one per i2
      float v0 = ftanh(qsel(cg4[0], quad) + gb0) * dwv;
      float v1 = ftanh(qsel(cg4[1], quad) + gb1) * dwv;
      float v2 = ftanh(qsel(cg4[2], quad) + gb2) * dwv;
      float v3 = ftanh(qsel(cg4[3], quad) + gb3v) * dwv;
      // butterfly allreduce within 8-lane groups (sum over n)
      v0 += __shfl_xor(v0, 1); v0 += __shfl_xor(v0, 2); v0 += __shfl_xor(v0, 4);
      v1 += __shfl_xor(v1, 1); v1 += __shfl_xor(v1, 2); v1 += __shfl_xor(v1, 4);
      v2 += __shfl_xor(v2, 1); v2 += __shfl_xor(v2, 2); v2 += __shfl_xor(v2, 4);
      v3 += __shfl_xor(v3, 1); v3 += __shfl_xor(v3, 2); v3 += __shfl_xor(v3, 4);
      // fetch f-term for owned column lstar
      float ftl = __shfl(ft, fsrc);
      float S = sel4(v0, v1, v2, v3, i2sel);
      if (writer) {
        zreg += S + ftl;
        zseg[zwaddr] = (_Float16)zreg;
      }
    }
    BAR();
  }

  // ---- final readout T=511 ----
  {
    half8 a0 = *(const half8*)(&zseg[ra]);
    half8 a1 = *(const half8*)(&zseg[512 + ra]);
    floatx4 cr = {0.f, 0.f, 0.f, 0.f};
    cr = mfma16(a0, Br1[0], cr); cr = mfma16(a1, Br1[1], cr);
    float vr = qsel(cr, quad);
    hrsg[haddr1] = (_Float16)fmaxf(vr + rb1v, 0.f);
  }
  BAR();
  if (w == 4) {
    half8 hr[4];
#pragma unroll
    for (int s = 0; s < 4; ++s) hr[s] = *(const half8*)(&hrsg[s * 512 + ra]);
    floatx4 co = {0.f, 0.f, 0.f, 0.f};
#pragma unroll
    for (int s = 0; s < 4; ++s) co = mfma16(hr[s], R2W[s], co);
    float v = qsel(co, quad) + rb2v;
    out_full[ofull4 + (size_t)511 * 16] = v;
  }
}

extern "C" void kernel_launch(void* const* d_in, const int* in_sizes, int n_in,
                              void* d_out, int out_size, void* d_ws, size_t ws_size,
                              hipStream_t stream) {
  (void)in_sizes; (void)n_in; (void)out_size; (void)ws_size;
  const float* init_noise = (const float*)d_in[0];
  const float* dw_noise   = (const float*)d_in[1];
  const float* emb_W      = (const float*)d_in[3];
  const float* emb_b      = (const float*)d_in[4];
  const float* f_W1       = (const float*)d_in[5];
  const float* f_b1       = (const float*)d_in[6];
  const float* f_W2       = (const float*)d_in[7];
  const float* f_b2       = (const float*)d_in[8];
  const float* f_W3       = (const float*)d_in[9];
  const float* f_b3       = (const float*)d_in[10];
  const float* g_W1       = (const float*)d_in[11];
  const float* g_b1       = (const float*)d_in[12];
  const float* g_W2       = (const float*)d_in[13];
  const float* g_b2       = (const float*)d_in[14];
  const float* g_W3       = (const float*)d_in[15];
  const float* g_b3       = (const float*)d_in[16];
  const float* r_W1       = (const float*)d_in[17];
  const float* r_b1       = (const float*)d_in[18];
  const float* r_W2       = (const float*)d_in[19];
  const float* r_b2       = (const float*)d_in[20];
  float* out_full = (float*)d_out;
  float* out_match = out_full + (size_t)1024 * 512 * 16;

  hipLaunchKernelGGL(prep_kernel, dim3((PREP_TOTAL + 255) / 256), dim3(256), 0, stream,
                     f_W1, g_W1, f_W2, g_W2, f_W3, g_W3, r_W1, r_W2, emb_W, d_ws);
  hipLaunchKernelGGL(sde_main, dim3(256), dim3(512), 0, stream,
                     init_noise, dw_noise, emb_b, f_b1, f_b2, f_b3,
                     g_b1, g_b2, g_b3, r_b1, r_b2, d_ws, out_full, out_match);
}

// Round 6
// 906.433 us; speedup vs baseline: 7.0163x; 1.0464x over previous
//
#include <hip/hip_runtime.h>
#include <cmath>

// ---------------------------------------------------------------------------
// Round 11. r10 (948us) was neutral vs r9 despite killing a barrier, an LDS
// round-trip and 100x bank conflicts -> step time is set by the SERIAL CHAIN
// inside each phase (2 lockstep waves/SIMD can't fill stalls). r11 cuts the
// chain tail + stragglers, no structural change:
//  1) U3 column remap: wave w loads fW3 cols 8w..8w+7 TWICE (lane ln16 ->
//     col 8w+(ln16&7)) => writer lane's own cf3 value IS its f-term. Deletes
//     the runtime-lane __shfl (ds_bpermute, ~100cyc) from P3's tail.
//  2) dW as per-lane register global load (each lane loads dW[quad][n8];
//     L1/L2 broadcast). Deletes dwS LDS + wave-7 special-case + dbuf logic.
//     Load issued in P1, consumed in P3, vmcnt never drained at barriers.
//  3) Butterfly -> reduce-scatter (exchange-what-partner-needs): 4 shuffles
//     + 6 cndmask + 4 adds vs 12 shuffles + 12 adds + sel4.
// Everything else = r10 (3 raw lgkm-only barriers/step, R2-MFMA on wave 4,
// quad-dup A-reads, reg-resident weights).
// ---------------------------------------------------------------------------

typedef _Float16 half8 __attribute__((ext_vector_type(8)));
typedef float floatx4 __attribute__((ext_vector_type(4)));

// ws layout: f16 region (offsets in _Float16 units)
#define H_FW1 0        // [128][64]
#define H_GW1 8192     // [128][64]
#define H_FW2 16384    // [128][128]
#define H_GW2 32768    // [128][128]
#define H_FW3 49152    // [64][128]
#define H_GW3 57344    // [512][128]
#define H_RW1 122880   // [128][64]
#define H_RW2 131072   // [16][128]  (f16 readout weights, transposed)
#define H_TOTAL 133120
// f32 region (offsets in float units from ws base; starts right after f16)
#define F_EMBT 66560             // [64][32]
#define F_W1R0F (F_EMBT + 2048)  // [128]
#define F_W1R0G (F_W1R0F + 128)  // [128]
#define F_CNT 2304
#define PREP_TOTAL (H_TOTAL + F_CNT)

__global__ void prep_kernel(const float* __restrict__ fW1, const float* __restrict__ gW1,
                            const float* __restrict__ fW2, const float* __restrict__ gW2,
                            const float* __restrict__ fW3, const float* __restrict__ gW3,
                            const float* __restrict__ rW1, const float* __restrict__ rW2,
                            const float* __restrict__ embW, void* __restrict__ ws) {
  int idx = blockIdx.x * blockDim.x + threadIdx.x;
  if (idx >= PREP_TOTAL) return;
  if (idx < H_TOTAL) {
    float v;
    if (idx < H_GW1) {
      int t = idx; int c = t >> 6, k = t & 63; v = fW1[(k + 1) * 128 + c];
    } else if (idx < H_FW2) {
      int t = idx - H_GW1; int c = t >> 6, k = t & 63; v = gW1[(k + 1) * 128 + c];
    } else if (idx < H_GW2) {
      int t = idx - H_FW2; int c = t >> 7, k = t & 127; v = fW2[k * 128 + c];
    } else if (idx < H_FW3) {
      int t = idx - H_GW2; int c = t >> 7, k = t & 127; v = gW2[k * 128 + c];
    } else if (idx < H_GW3) {
      int t = idx - H_FW3; int c = t >> 7, k = t & 127; v = fW3[k * 64 + c];
    } else if (idx < H_RW1) {
      int t = idx - H_GW3; int c = t >> 7, k = t & 127; v = gW3[k * 512 + c];
    } else if (idx < H_RW2) {
      int t = idx - H_RW1; int c = t >> 6, k = t & 63; v = rW1[k * 128 + c];
    } else {
      int t = idx - H_RW2; int c = t >> 7, k = t & 127; v = rW2[k * 16 + c];
    }
    ((_Float16*)ws)[idx] = (_Float16)v;
  } else {
    int f = idx - H_TOTAL;
    float v;
    if (f < 2048) {
      int c = f >> 5, k = f & 31; v = embW[k * 64 + c];
      ((float*)ws)[F_EMBT + f] = v;
    } else if (f < 2176) {
      ((float*)ws)[F_W1R0F + (f - 2048)] = fW1[f - 2048];
    } else {
      ((float*)ws)[F_W1R0G + (f - 2176)] = gW1[f - 2176];
    }
  }
}

__device__ __forceinline__ float sp(float x) { return __logf(1.f + __expf(x)); }

// clamp-free tanh: exp(2x)->inf gives 1-0=1; exp(2x)->0 gives 1-2=-1.
__device__ __forceinline__ float ftanh(float x) {
  float e = __expf(2.f * x);
  return 1.f - __fdividef(2.f, e + 1.f);
}

__device__ __forceinline__ floatx4 mfma16(half8 a, half8 b, floatx4 c) {
  return __builtin_amdgcn_mfma_f32_16x16x32_f16(a, b, c, 0, 0, 0);
}

// lane-linear A-layout with sub-k bank shift.
// element (m,k): seg(k>>5)*512 + subk*128 + (subk&1)*32 + m*8 + (k&7)
__device__ __forceinline__ int aofs2(int m, int k) {
  int subk = (k >> 3) & 3;
  return ((k >> 5) << 9) + (subk << 7) + ((subk & 1) << 5) + (m << 3) + (k & 7);
}

// select element `quad` of a floatx4 with static indices (rule #20 safe)
__device__ __forceinline__ float qsel(floatx4 c, int quad) {
  float v01 = (quad & 1) ? c[1] : c[0];
  float v23 = (quad & 1) ? c[3] : c[2];
  return (quad & 2) ? v23 : v01;
}

// Raw phase barrier: LDS-ordering only; vmcnt left in flight on purpose.
#define BAR()                                                    \
  do {                                                           \
    asm volatile("s_waitcnt lgkmcnt(0)" ::: "memory");           \
    __builtin_amdgcn_s_barrier();                                \
    asm volatile("" ::: "memory");                               \
  } while (0)

__global__ __launch_bounds__(512, 2)
void sde_main(const float* __restrict__ init_noise, const float* __restrict__ dw_noise,
              const float* __restrict__ emb_b,
              const float* __restrict__ f_b1, const float* __restrict__ f_b2,
              const float* __restrict__ f_b3, const float* __restrict__ g_b1,
              const float* __restrict__ g_b2, const float* __restrict__ g_b3,
              const float* __restrict__ r_b1, const float* __restrict__ r_b2,
              const void* __restrict__ ws, float* __restrict__ out_full,
              float* __restrict__ out_match) {
  // lane-linear f16 activation buffers (rows 0-3 real, duplicated reads)
  __shared__ __align__(16) _Float16 zseg[1024];                 // z, K=64
  __shared__ __align__(16) _Float16 h1f[2048], h1g[2048];       // K=128
  __shared__ __align__(16) _Float16 h2f[2048], h2g[2048];
  __shared__ __align__(16) _Float16 hrsg[2048];                 // readout hidden (f16)
  // f32 scratch (pre-loop staging only)
  __shared__ __align__(16) float zb[4 * 68];      // z0 staging
  __shared__ __align__(16) float stg[4 * 36];     // init_noise staging

  const int tid = threadIdx.x;
  const int w = tid >> 6;          // wave 0..7
  const int lane = tid & 63;
  const int ln16 = lane & 15;
  const int quad = lane >> 4;
  const int koff = quad * 8;
  const int wm = w & 3;
  const int b4 = blockIdx.x << 2;
  const _Float16* wsh = (const _Float16*)ws;
  const float* wsf = (const float*)ws;

  const float DTI = 1.0f / 511.0f;
  const float SDT = sqrtf(DTI);

  // ---- step-invariant per-lane constants (registers) ----
  const int col1 = w * 16 + ln16;                 // P1/R1 column
  const float b1fv = f_b1[col1], b1gv = g_b1[col1];
  const float w1fv = wsf[F_W1R0F + col1], w1gv = wsf[F_W1R0G + col1];
  const float rb1v = r_b1[col1];
  const int colA = wm * 32 + ln16, colB = colA + 16;  // P2 columns
  const float* bsrc2 = (w < 4) ? f_b2 : g_b2;
  const float b2vA = bsrc2[colA], b2vB = bsrc2[colB];
  // duplicated A-read offset (within a 512-f16 seg)
  const int ra = ((lane >> 4) << 7) + (((lane >> 4) & 1) << 5) + ((lane & 3) << 3);
  // write addresses
  const int haddr1 = aofs2(quad, col1);
  const int haddr2A = aofs2(quad, colA), haddr2B = aofs2(quad, colB);
  // P3 z-update constants
  const int n8 = ln16 & 7;                   // noise index for this lane
  const int hlf = ln16 >> 3;                 // which half of the 16-group
  const bool writer = ((n8 & 1) == hlf);     // owner of z(quad, lstar)
  const int lstar = (w << 3) + n8;           // owned z column
  const int zwaddr = aofs2(quad, lstar);
  const int fcol = (w << 3) + n8;            // fW3 column (cols 8w..8w+7, x2)
  const float fb3v = f_b3[fcol];
  const float gb0 = g_b3[w * 64 + 0 * 16 + ln16];
  const float gb1 = g_b3[w * 64 + 1 * 16 + ln16];
  const float gb2 = g_b3[w * 64 + 2 * 16 + ln16];
  const float gb3v = g_b3[w * 64 + 3 * 16 + ln16];
  // per-lane dW source offset: dW[row=quad][n=n8]
  const int dwofs_g = (b4 + quad) * 8 + n8;
  // R2-MFMA constants (wave 4): lane (quad,ln16) stores row quad, dim ln16
  const float rb2v = r_b2[ln16];
  const size_t ofull4 = ((size_t)(b4 + quad) * 512) * 16 + ln16;
  const size_t omatch4 = ((size_t)(b4 + quad) * 64) * 16 + ln16;

  // ---- init: stage init_noise (f32) ----
  if (tid < 128) stg[(tid >> 5) * 36 + (tid & 31)] = init_noise[b4 * 32 + tid];

  // ---- persistent B-fragments (VGPR/AGPR-resident for all 511 steps) ----
  // U3: fW3 cols 8w..8w+7 duplicated (P3); R2W: rW2 tile (wave 4, P2/final)
  half8 Bf1[2], Bg1[2], Br1[2], B2[2][4], B3g[4][4], U3[4], R2W[4];
#pragma unroll
  for (int kf = 0; kf < 2; ++kf) {
    Bf1[kf] = *(const half8*)(wsh + H_FW1 + col1 * 64 + kf * 32 + koff);
    Bg1[kf] = *(const half8*)(wsh + H_GW1 + col1 * 64 + kf * 32 + koff);
    Br1[kf] = *(const half8*)(wsh + H_RW1 + col1 * 64 + kf * 32 + koff);
  }
  const _Float16* w2b = wsh + (w < 4 ? H_FW2 : H_GW2);
#pragma unroll
  for (int i2 = 0; i2 < 2; ++i2)
#pragma unroll
    for (int kf = 0; kf < 4; ++kf)
      B2[i2][kf] = *(const half8*)(w2b + ((wm * 2 + i2) * 16 + ln16) * 128 + kf * 32 + koff);
#pragma unroll
  for (int i2 = 0; i2 < 4; ++i2)
#pragma unroll
    for (int kf = 0; kf < 4; ++kf)
      B3g[i2][kf] = *(const half8*)(wsh + H_GW3 + ((w * 4 + i2) * 16 + ln16) * 128 + kf * 32 + koff);
#pragma unroll
  for (int kf = 0; kf < 4; ++kf) {
    U3[kf] = *(const half8*)(wsh + H_FW3 + fcol * 128 + kf * 32 + koff);
    R2W[kf] = *(const half8*)(wsh + H_RW2 + ln16 * 128 + kf * 32 + koff);
  }
  __syncthreads();

  // ---- z0 = init_noise @ emb_W + emb_b ----
  if (tid < 256) {
    const int rr = tid & 3, l = tid >> 2;
    const float* pe = wsf + F_EMBT + l * 32;
    float acc = emb_b[l];
#pragma unroll
    for (int c = 0; c < 8; ++c) {
      float4 a = *(const float4*)(&stg[rr * 36 + 4 * c]);
      float4 v = *(const float4*)(pe + 4 * c);
      acc += a.x * v.x + a.y * v.y + a.z * v.z + a.w * v.w;
    }
    zb[rr * 68 + l] = acc;
    zseg[aofs2(rr, l)] = (_Float16)acc;
  }
  __syncthreads();

  // z f32 state lives in the owner lane's register
  float zreg = writer ? zb[quad * 68 + lstar] : 0.f;

  // per-lane dW register pipeline: dwv = step i's weight (incl. SDT)
  float dwv = dw_noise[dwofs_g] * SDT;
  float dwn = 0.f;

#pragma unroll 1
  for (int i = 0; i < 511; ++i) {
    const float t_s = (float)i * DTI;

    // ---- P1: L1 (f,g) + R1 sharing z A-frags; issue dW(i+1) load ----
    {
      half8 a0 = *(const half8*)(&zseg[ra]);
      half8 a1 = *(const half8*)(&zseg[512 + ra]);
      {
        int ip = (i < 510) ? i + 1 : 510;
        dwn = dw_noise[(size_t)ip * 8192 + dwofs_g];
      }
      floatx4 cf = {0.f, 0.f, 0.f, 0.f}, cg = {0.f, 0.f, 0.f, 0.f}, cr = {0.f, 0.f, 0.f, 0.f};
      cf = mfma16(a0, Bf1[0], cf); cf = mfma16(a1, Bf1[1], cf);
      cg = mfma16(a0, Bg1[0], cg); cg = mfma16(a1, Bg1[1], cg);
      cr = mfma16(a0, Br1[0], cr); cr = mfma16(a1, Br1[1], cr);
      float vf = qsel(cf, quad), vg = qsel(cg, quad), vr = qsel(cr, quad);
      h1f[haddr1] = (_Float16)sp(vf + b1fv + t_s * w1fv);
      h1g[haddr1] = (_Float16)sp(vg + b1gv + t_s * w1gv);
      hrsg[haddr1] = (_Float16)fmaxf(vr + rb1v, 0.f);
    }
    BAR();

    // ---- P2: L2 (waves 0-3 f, 4-7 g) + R2-MFMA (wave 4) ----
    {
      const _Float16* asrc = (w < 4) ? h1f : h1g;
      half8 a[4];
#pragma unroll
      for (int s = 0; s < 4; ++s) a[s] = *(const half8*)(&asrc[s * 512 + ra]);
      floatx4 c0 = {0.f, 0.f, 0.f, 0.f}, c1 = {0.f, 0.f, 0.f, 0.f};
#pragma unroll
      for (int s = 0; s < 4; ++s) {
        c0 = mfma16(a[s], B2[0][s], c0);
        c1 = mfma16(a[s], B2[1][s], c1);
      }
      if (w == 4) {
        half8 hr[4];
#pragma unroll
        for (int s = 0; s < 4; ++s) hr[s] = *(const half8*)(&hrsg[s * 512 + ra]);
        floatx4 co = {0.f, 0.f, 0.f, 0.f};
#pragma unroll
        for (int s = 0; s < 4; ++s) co = mfma16(hr[s], R2W[s], co);
        float v = qsel(co, quad) + rb2v;
        out_full[ofull4 + (size_t)i * 16] = v;
        if ((i & 7) == 0) out_match[omatch4 + (size_t)(i >> 3) * 16] = v;
      }
      _Float16* dst = (w < 4) ? h2f : h2g;
      float v0 = qsel(c0, quad), v1 = qsel(c1, quad);
      dst[haddr2A] = (_Float16)sp(v0 + b2vA);
      dst[haddr2B] = (_Float16)sp(v1 + b2vB);
    }
    BAR();

    // ---- P3: L3 g (4 tiles) + L3 f (dup cols 8w..8w+7) + fused z-update ----
    {
      half8 ag[4];
#pragma unroll
      for (int s = 0; s < 4; ++s) ag[s] = *(const half8*)(&h2g[s * 512 + ra]);
      floatx4 cg4[4];
#pragma unroll
      for (int i2 = 0; i2 < 4; ++i2) cg4[i2] = (floatx4){0.f, 0.f, 0.f, 0.f};
#pragma unroll
      for (int s = 0; s < 4; ++s)
#pragma unroll
        for (int i2 = 0; i2 < 4; ++i2) cg4[i2] = mfma16(ag[s], B3g[i2][s], cg4[i2]);
      floatx4 cf3 = {0.f, 0.f, 0.f, 0.f};
#pragma unroll
      for (int s = 0; s < 4; ++s) {
        half8 af = *(const half8*)(&h2f[s * 512 + ra]);
        cf3 = mfma16(af, U3[s], cf3);
      }
      // f-term: lane's own column fcol = 8w+n8 == writer's lstar
      float ft = ftanh(qsel(cf3, quad) + fb3v) * DTI;
      // weighted g-terms, one per i2 (dwv = dW[quad][n8]*SDT, register)
      float v0 = ftanh(qsel(cg4[0], quad) + gb0) * dwv;
      float v1 = ftanh(qsel(cg4[1], quad) + gb1) * dwv;
      float v2 = ftanh(qsel(cg4[2], quad) + gb2) * dwv;
      float v3 = ftanh(qsel(cg4[3], quad) + gb3v) * dwv;
      // reduce-scatter over 8-lane group: lane n8 ends with sum for i2=n8>>1
      float s0 = (n8 & 4) ? v0 : v2;
      float s1 = (n8 & 4) ? v1 : v3;
      float r0 = __shfl_xor(s0, 4);
      float r1 = __shfl_xor(s1, 4);
      float pa = ((n8 & 4) ? v2 : v0) + r0;
      float pb = ((n8 & 4) ? v3 : v1) + r1;
      float u = (n8 & 2) ? pa : pb;
      float ru = __shfl_xor(u, 2);
      float sv = ((n8 & 2) ? pb : pa) + ru;
      float S = sv + __shfl_xor(sv, 1);
      if (writer) {
        zreg += S + ft;
        zseg[zwaddr] = (_Float16)zreg;
      }
    }
    BAR();

    dwv = dwn * SDT;  // step i+1's weight (load issued back in P1, hidden)
  }

  // ---- final readout T=511 ----
  {
    half8 a0 = *(const half8*)(&zseg[ra]);
    half8 a1 = *(const half8*)(&zseg[512 + ra]);
    floatx4 cr = {0.f, 0.f, 0.f, 0.f};
    cr = mfma16(a0, Br1[0], cr); cr = mfma16(a1, Br1[1], cr);
    float vr = qsel(cr, quad);
    hrsg[haddr1] = (_Float16)fmaxf(vr + rb1v, 0.f);
  }
  BAR();
  if (w == 4) {
    half8 hr[4];
#pragma unroll
    for (int s = 0; s < 4; ++s) hr[s] = *(const half8*)(&hrsg[s * 512 + ra]);
    floatx4 co = {0.f, 0.f, 0.f, 0.f};
#pragma unroll
    for (int s = 0; s < 4; ++s) co = mfma16(hr[s], R2W[s], co);
    float v = qsel(co, quad) + rb2v;
    out_full[ofull4 + (size_t)511 * 16] = v;
  }
}

extern "C" void kernel_launch(void* const* d_in, const int* in_sizes, int n_in,
                              void* d_out, int out_size, void* d_ws, size_t ws_size,
                              hipStream_t stream) {
  (void)in_sizes; (void)n_in; (void)out_size; (void)ws_size;
  const float* init_noise = (const float*)d_in[0];
  const float* dw_noise   = (const float*)d_in[1];
  const float* emb_W      = (const float*)d_in[3];
  const float* emb_b      = (const float*)d_in[4];
  const float* f_W1       = (const float*)d_in[5];
  const float* f_b1       = (const float*)d_in[6];
  const float* f_W2       = (const float*)d_in[7];
  const float* f_b2       = (const float*)d_in[8];
  const float* f_W3       = (const float*)d_in[9];
  const float* f_b3       = (const float*)d_in[10];
  const float* g_W1       = (const float*)d_in[11];
  const float* g_b1       = (const float*)d_in[12];
  const float* g_W2       = (const float*)d_in[13];
  const float* g_b2       = (const float*)d_in[14];
  const float* g_W3       = (const float*)d_in[15];
  const float* g_b3       = (const float*)d_in[16];
  const float* r_W1       = (const float*)d_in[17];
  const float* r_b1       = (const float*)d_in[18];
  const float* r_W2       = (const float*)d_in[19];
  const float* r_b2       = (const float*)d_in[20];
  float* out_full = (float*)d_out;
  float* out_match = out_full + (size_t)1024 * 512 * 16;

  hipLaunchKernelGGL(prep_kernel, dim3((PREP_TOTAL + 255) / 256), dim3(256), 0, stream,
                     f_W1, g_W1, f_W2, g_W2, f_W3, g_W3, r_W1, r_W2, emb_W, d_ws);
  hipLaunchKernelGGL(sde_main, dim3(256), dim3(512), 0, stream,
                     init_noise, dw_noise, emb_b, f_b1, f_b2, f_b3,
                     g_b1, g_b2, g_b3, r_b1, r_b2, d_ws, out_full, out_match);
}

// Round 8
// 865.989 us; speedup vs baseline: 7.3440x; 1.0467x over previous
//
#include <hip/hip_runtime.h>
#include <cmath>

// ---------------------------------------------------------------------------
// Round 13 = r12 re-run (previous bench died with "MI355X container failed
// twice" -- infra error, no kernel result). Kernel identical to r12:
//  1) DPP reduce-scatter: the 8-lane noise-sum's xor1/xor2/half-pair rounds
//     become VALU DPP permutes (quad_perm 0xB1/0x4E, row_half_mirror 0x141)
//     -- removes 4 LDS-pipe shuffles + their lgkm drain from the serial path
//     between the last tanh and the z-write that gates next step's P1.
//  2) cf3 split into two independent 2-MFMA chains, combined per-element at
//     qsel time (+3 VALU, -2 dependent MFMA latencies on the f-term path).
// Base = r11 (906us): 3 raw lgkm-only barriers/step, R2-MFMA on wave 4,
// quad-dup A-reads, reg-resident weights, per-lane dW register pipeline,
// fW3 col remap (writer lane owns its f-term).
// ---------------------------------------------------------------------------

typedef _Float16 half8 __attribute__((ext_vector_type(8)));
typedef float floatx4 __attribute__((ext_vector_type(4)));

// ws layout: f16 region (offsets in _Float16 units)
#define H_FW1 0        // [128][64]
#define H_GW1 8192     // [128][64]
#define H_FW2 16384    // [128][128]
#define H_GW2 32768    // [128][128]
#define H_FW3 49152    // [64][128]
#define H_GW3 57344    // [512][128]
#define H_RW1 122880   // [128][64]
#define H_RW2 131072   // [16][128]  (f16 readout weights, transposed)
#define H_TOTAL 133120
// f32 region (offsets in float units from ws base; starts right after f16)
#define F_EMBT 66560             // [64][32]
#define F_W1R0F (F_EMBT + 2048)  // [128]
#define F_W1R0G (F_W1R0F + 128)  // [128]
#define F_CNT 2304
#define PREP_TOTAL (H_TOTAL + F_CNT)

__global__ void prep_kernel(const float* __restrict__ fW1, const float* __restrict__ gW1,
                            const float* __restrict__ fW2, const float* __restrict__ gW2,
                            const float* __restrict__ fW3, const float* __restrict__ gW3,
                            const float* __restrict__ rW1, const float* __restrict__ rW2,
                            const float* __restrict__ embW, void* __restrict__ ws) {
  int idx = blockIdx.x * blockDim.x + threadIdx.x;
  if (idx >= PREP_TOTAL) return;
  if (idx < H_TOTAL) {
    float v;
    if (idx < H_GW1) {
      int t = idx; int c = t >> 6, k = t & 63; v = fW1[(k + 1) * 128 + c];
    } else if (idx < H_FW2) {
      int t = idx - H_GW1; int c = t >> 6, k = t & 63; v = gW1[(k + 1) * 128 + c];
    } else if (idx < H_GW2) {
      int t = idx - H_FW2; int c = t >> 7, k = t & 127; v = fW2[k * 128 + c];
    } else if (idx < H_FW3) {
      int t = idx - H_GW2; int c = t >> 7, k = t & 127; v = gW2[k * 128 + c];
    } else if (idx < H_GW3) {
      int t = idx - H_FW3; int c = t >> 7, k = t & 127; v = fW3[k * 64 + c];
    } else if (idx < H_RW1) {
      int t = idx - H_GW3; int c = t >> 7, k = t & 127; v = gW3[k * 512 + c];
    } else if (idx < H_RW2) {
      int t = idx - H_RW1; int c = t >> 6, k = t & 63; v = rW1[k * 128 + c];
    } else {
      int t = idx - H_RW2; int c = t >> 7, k = t & 127; v = rW2[k * 16 + c];
    }
    ((_Float16*)ws)[idx] = (_Float16)v;
  } else {
    int f = idx - H_TOTAL;
    float v;
    if (f < 2048) {
      int c = f >> 5, k = f & 31; v = embW[k * 64 + c];
      ((float*)ws)[F_EMBT + f] = v;
    } else if (f < 2176) {
      ((float*)ws)[F_W1R0F + (f - 2048)] = fW1[f - 2048];
    } else {
      ((float*)ws)[F_W1R0G + (f - 2176)] = gW1[f - 2176];
    }
  }
}

__device__ __forceinline__ float sp(float x) { return __logf(1.f + __expf(x)); }

// clamp-free tanh: exp(2x)->inf gives 1-0=1; exp(2x)->0 gives 1-2=-1.
__device__ __forceinline__ float ftanh(float x) {
  float e = __expf(2.f * x);
  return 1.f - __fdividef(2.f, e + 1.f);
}

__device__ __forceinline__ floatx4 mfma16(half8 a, half8 b, floatx4 c) {
  return __builtin_amdgcn_mfma_f32_16x16x32_f16(a, b, c, 0, 0, 0);
}

// lane-linear A-layout with sub-k bank shift.
// element (m,k): seg(k>>5)*512 + subk*128 + (subk&1)*32 + m*8 + (k&7)
__device__ __forceinline__ int aofs2(int m, int k) {
  int subk = (k >> 3) & 3;
  return ((k >> 5) << 9) + (subk << 7) + ((subk & 1) << 5) + (m << 3) + (k & 7);
}

// select element `quad` of a floatx4 with static indices (rule #20 safe)
__device__ __forceinline__ float qsel(floatx4 c, int quad) {
  float v01 = (quad & 1) ? c[1] : c[0];
  float v23 = (quad & 1) ? c[3] : c[2];
  return (quad & 2) ? v23 : v01;
}

// DPP lane-permute mov (VALU pipe; no LDS). CTRL: 0xB1=xor1 (quad_perm
// [1,0,3,2]), 0x4E=xor2 ([2,3,0,1]), 0x141=row_half_mirror (l <-> 7-l
// within each aligned 8-lane group).
template <int CTRL>
__device__ __forceinline__ float dppmov(float v) {
  return __builtin_bit_cast(float,
      __builtin_amdgcn_update_dpp(0, __builtin_bit_cast(int, v), CTRL, 0xF, 0xF, true));
}

// Raw phase barrier: LDS-ordering only; vmcnt left in flight on purpose.
#define BAR()                                                    \
  do {                                                           \
    asm volatile("s_waitcnt lgkmcnt(0)" ::: "memory");           \
    __builtin_amdgcn_s_barrier();                                \
    asm volatile("" ::: "memory");                               \
  } while (0)

__global__ __launch_bounds__(512, 2)
void sde_main(const float* __restrict__ init_noise, const float* __restrict__ dw_noise,
              const float* __restrict__ emb_b,
              const float* __restrict__ f_b1, const float* __restrict__ f_b2,
              const float* __restrict__ f_b3, const float* __restrict__ g_b1,
              const float* __restrict__ g_b2, const float* __restrict__ g_b3,
              const float* __restrict__ r_b1, const float* __restrict__ r_b2,
              const void* __restrict__ ws, float* __restrict__ out_full,
              float* __restrict__ out_match) {
  // lane-linear f16 activation buffers (rows 0-3 real, duplicated reads)
  __shared__ __align__(16) _Float16 zseg[1024];                 // z, K=64
  __shared__ __align__(16) _Float16 h1f[2048], h1g[2048];       // K=128
  __shared__ __align__(16) _Float16 h2f[2048], h2g[2048];
  __shared__ __align__(16) _Float16 hrsg[2048];                 // readout hidden (f16)
  // f32 scratch (pre-loop staging only)
  __shared__ __align__(16) float zb[4 * 68];      // z0 staging
  __shared__ __align__(16) float stg[4 * 36];     // init_noise staging

  const int tid = threadIdx.x;
  const int w = tid >> 6;          // wave 0..7
  const int lane = tid & 63;
  const int ln16 = lane & 15;
  const int quad = lane >> 4;
  const int koff = quad * 8;
  const int wm = w & 3;
  const int b4 = blockIdx.x << 2;
  const _Float16* wsh = (const _Float16*)ws;
  const float* wsf = (const float*)ws;

  const float DTI = 1.0f / 511.0f;
  const float SDT = sqrtf(DTI);

  // ---- step-invariant per-lane constants (registers) ----
  const int col1 = w * 16 + ln16;                 // P1/R1 column
  const float b1fv = f_b1[col1], b1gv = g_b1[col1];
  const float w1fv = wsf[F_W1R0F + col1], w1gv = wsf[F_W1R0G + col1];
  const float rb1v = r_b1[col1];
  const int colA = wm * 32 + ln16, colB = colA + 16;  // P2 columns
  const float* bsrc2 = (w < 4) ? f_b2 : g_b2;
  const float b2vA = bsrc2[colA], b2vB = bsrc2[colB];
  // duplicated A-read offset (within a 512-f16 seg)
  const int ra = ((lane >> 4) << 7) + (((lane >> 4) & 1) << 5) + ((lane & 3) << 3);
  // write addresses
  const int haddr1 = aofs2(quad, col1);
  const int haddr2A = aofs2(quad, colA), haddr2B = aofs2(quad, colB);
  // P3 z-update constants
  const int n8 = ln16 & 7;                   // noise index for this lane
  const int hlf = ln16 >> 3;                 // which half of the 16-group
  const bool writer = ((n8 & 1) == hlf);     // owner of z(quad, lstar)
  const int lstar = (w << 3) + n8;           // owned z column
  const int zwaddr = aofs2(quad, lstar);
  const int fcol = (w << 3) + n8;            // fW3 column (cols 8w..8w+7, x2)
  const float fb3v = f_b3[fcol];
  const float gb0 = g_b3[w * 64 + 0 * 16 + ln16];
  const float gb1 = g_b3[w * 64 + 1 * 16 + ln16];
  const float gb2 = g_b3[w * 64 + 2 * 16 + ln16];
  const float gb3v = g_b3[w * 64 + 3 * 16 + ln16];
  // per-lane dW source offset: dW[row=quad][n=n8]
  const int dwofs_g = (b4 + quad) * 8 + n8;
  // R2-MFMA constants (wave 4): lane (quad,ln16) stores row quad, dim ln16
  const float rb2v = r_b2[ln16];
  const size_t ofull4 = ((size_t)(b4 + quad) * 512) * 16 + ln16;
  const size_t omatch4 = ((size_t)(b4 + quad) * 64) * 16 + ln16;

  // ---- init: stage init_noise (f32) ----
  if (tid < 128) stg[(tid >> 5) * 36 + (tid & 31)] = init_noise[b4 * 32 + tid];

  // ---- persistent B-fragments (VGPR/AGPR-resident for all 511 steps) ----
  // U3: fW3 cols 8w..8w+7 duplicated (P3); R2W: rW2 tile (wave 4, P2/final)
  half8 Bf1[2], Bg1[2], Br1[2], B2[2][4], B3g[4][4], U3[4], R2W[4];
#pragma unroll
  for (int kf = 0; kf < 2; ++kf) {
    Bf1[kf] = *(const half8*)(wsh + H_FW1 + col1 * 64 + kf * 32 + koff);
    Bg1[kf] = *(const half8*)(wsh + H_GW1 + col1 * 64 + kf * 32 + koff);
    Br1[kf] = *(const half8*)(wsh + H_RW1 + col1 * 64 + kf * 32 + koff);
  }
  const _Float16* w2b = wsh + (w < 4 ? H_FW2 : H_GW2);
#pragma unroll
  for (int i2 = 0; i2 < 2; ++i2)
#pragma unroll
    for (int kf = 0; kf < 4; ++kf)
      B2[i2][kf] = *(const half8*)(w2b + ((wm * 2 + i2) * 16 + ln16) * 128 + kf * 32 + koff);
#pragma unroll
  for (int i2 = 0; i2 < 4; ++i2)
#pragma unroll
    for (int kf = 0; kf < 4; ++kf)
      B3g[i2][kf] = *(const half8*)(wsh + H_GW3 + ((w * 4 + i2) * 16 + ln16) * 128 + kf * 32 + koff);
#pragma unroll
  for (int kf = 0; kf < 4; ++kf) {
    U3[kf] = *(const half8*)(wsh + H_FW3 + fcol * 128 + kf * 32 + koff);
    R2W[kf] = *(const half8*)(wsh + H_RW2 + ln16 * 128 + kf * 32 + koff);
  }
  __syncthreads();

  // ---- z0 = init_noise @ emb_W + emb_b ----
  if (tid < 256) {
    const int rr = tid & 3, l = tid >> 2;
    const float* pe = wsf + F_EMBT + l * 32;
    float acc = emb_b[l];
#pragma unroll
    for (int c = 0; c < 8; ++c) {
      float4 a = *(const float4*)(&stg[rr * 36 + 4 * c]);
      float4 v = *(const float4*)(pe + 4 * c);
      acc += a.x * v.x + a.y * v.y + a.z * v.z + a.w * v.w;
    }
    zb[rr * 68 + l] = acc;
    zseg[aofs2(rr, l)] = (_Float16)acc;
  }
  __syncthreads();

  // z f32 state lives in the owner lane's register
  float zreg = writer ? zb[quad * 68 + lstar] : 0.f;

  // per-lane dW register pipeline: dwv = step i's weight (incl. SDT)
  float dwv = dw_noise[dwofs_g] * SDT;
  float dwn = 0.f;

#pragma unroll 1
  for (int i = 0; i < 511; ++i) {
    const float t_s = (float)i * DTI;

    // ---- P1: L1 (f,g) + R1 sharing z A-frags; issue dW(i+1) load ----
    {
      half8 a0 = *(const half8*)(&zseg[ra]);
      half8 a1 = *(const half8*)(&zseg[512 + ra]);
      {
        int ip = (i < 510) ? i + 1 : 510;
        dwn = dw_noise[(size_t)ip * 8192 + dwofs_g];
      }
      floatx4 cf = {0.f, 0.f, 0.f, 0.f}, cg = {0.f, 0.f, 0.f, 0.f}, cr = {0.f, 0.f, 0.f, 0.f};
      cf = mfma16(a0, Bf1[0], cf); cf = mfma16(a1, Bf1[1], cf);
      cg = mfma16(a0, Bg1[0], cg); cg = mfma16(a1, Bg1[1], cg);
      cr = mfma16(a0, Br1[0], cr); cr = mfma16(a1, Br1[1], cr);
      float vf = qsel(cf, quad), vg = qsel(cg, quad), vr = qsel(cr, quad);
      h1f[haddr1] = (_Float16)sp(vf + b1fv + t_s * w1fv);
      h1g[haddr1] = (_Float16)sp(vg + b1gv + t_s * w1gv);
      hrsg[haddr1] = (_Float16)fmaxf(vr + rb1v, 0.f);
    }
    BAR();

    // ---- P2: L2 (waves 0-3 f, 4-7 g) + R2-MFMA (wave 4) ----
    {
      const _Float16* asrc = (w < 4) ? h1f : h1g;
      half8 a[4];
#pragma unroll
      for (int s = 0; s < 4; ++s) a[s] = *(const half8*)(&asrc[s * 512 + ra]);
      floatx4 c0 = {0.f, 0.f, 0.f, 0.f}, c1 = {0.f, 0.f, 0.f, 0.f};
#pragma unroll
      for (int s = 0; s < 4; ++s) {
        c0 = mfma16(a[s], B2[0][s], c0);
        c1 = mfma16(a[s], B2[1][s], c1);
      }
      if (w == 4) {
        half8 hr[4];
#pragma unroll
        for (int s = 0; s < 4; ++s) hr[s] = *(const half8*)(&hrsg[s * 512 + ra]);
        floatx4 co = {0.f, 0.f, 0.f, 0.f};
#pragma unroll
        for (int s = 0; s < 4; ++s) co = mfma16(hr[s], R2W[s], co);
        float v = qsel(co, quad) + rb2v;
        out_full[ofull4 + (size_t)i * 16] = v;
        if ((i & 7) == 0) out_match[omatch4 + (size_t)(i >> 3) * 16] = v;
      }
      _Float16* dst = (w < 4) ? h2f : h2g;
      float v0 = qsel(c0, quad), v1 = qsel(c1, quad);
      dst[haddr2A] = (_Float16)sp(v0 + b2vA);
      dst[haddr2B] = (_Float16)sp(v1 + b2vB);
    }
    BAR();

    // ---- P3: L3 g (4 tiles) + L3 f (split chains) + fused z-update ----
    {
      half8 ag[4];
#pragma unroll
      for (int s = 0; s < 4; ++s) ag[s] = *(const half8*)(&h2g[s * 512 + ra]);
      floatx4 cg4[4];
#pragma unroll
      for (int i2 = 0; i2 < 4; ++i2) cg4[i2] = (floatx4){0.f, 0.f, 0.f, 0.f};
#pragma unroll
      for (int s = 0; s < 4; ++s)
#pragma unroll
        for (int i2 = 0; i2 < 4; ++i2) cg4[i2] = mfma16(ag[s], B3g[i2][s], cg4[i2]);
      // f-chain split: two independent 2-MFMA chains, combined per-element
      floatx4 cfa = {0.f, 0.f, 0.f, 0.f}, cfb = {0.f, 0.f, 0.f, 0.f};
      {
        half8 af0 = *(const half8*)(&h2f[0 * 512 + ra]);
        half8 af1 = *(const half8*)(&h2f[1 * 512 + ra]);
        half8 af2 = *(const half8*)(&h2f[2 * 512 + ra]);
        half8 af3 = *(const half8*)(&h2f[3 * 512 + ra]);
        cfa = mfma16(af0, U3[0], cfa); cfa = mfma16(af1, U3[1], cfa);
        cfb = mfma16(af2, U3[2], cfb); cfb = mfma16(af3, U3[3], cfb);
      }
      // f-term: lane's own column fcol = 8w+n8 == writer's lstar
      float ft = ftanh(qsel(cfa, quad) + qsel(cfb, quad) + fb3v) * DTI;
      // weighted g-terms, one per i2 (dwv = dW[quad][n8]*SDT, register)
      float v0 = ftanh(qsel(cg4[0], quad) + gb0) * dwv;
      float v1 = ftanh(qsel(cg4[1], quad) + gb1) * dwv;
      float v2 = ftanh(qsel(cg4[2], quad) + gb2) * dwv;
      float v3 = ftanh(qsel(cg4[3], quad) + gb3v) * dwv;
      // DPP reduce-scatter over 8-lane group (VALU-only, no LDS):
      // round 1: half-pair exchange (l <-> 7-l), send what partner needs
      float s0 = (n8 & 4) ? v0 : v2;
      float s1 = (n8 & 4) ? v1 : v3;
      float pa = ((n8 & 4) ? v2 : v0) + dppmov<0x141>(s0);
      float pb = ((n8 & 4) ? v3 : v1) + dppmov<0x141>(s1);
      // round 2: xor2 within 4-group
      float u = (n8 & 2) ? pa : pb;
      float sv = ((n8 & 2) ? pb : pa) + dppmov<0x4E>(u);
      // round 3: xor1
      float S = sv + dppmov<0xB1>(sv);
      if (writer) {
        zreg += S + ft;
        zseg[zwaddr] = (_Float16)zreg;
      }
    }
    BAR();

    dwv = dwn * SDT;  // step i+1's weight (load issued back in P1, hidden)
  }

  // ---- final readout T=511 ----
  {
    half8 a0 = *(const half8*)(&zseg[ra]);
    half8 a1 = *(const half8*)(&zseg[512 + ra]);
    floatx4 cr = {0.f, 0.f, 0.f, 0.f};
    cr = mfma16(a0, Br1[0], cr); cr = mfma16(a1, Br1[1], cr);
    float vr = qsel(cr, quad);
    hrsg[haddr1] = (_Float16)fmaxf(vr + rb1v, 0.f);
  }
  BAR();
  if (w == 4) {
    half8 hr[4];
#pragma unroll
    for (int s = 0; s < 4; ++s) hr[s] = *(const half8*)(&hrsg[s * 512 + ra]);
    floatx4 co = {0.f, 0.f, 0.f, 0.f};
#pragma unroll
    for (int s = 0; s < 4; ++s) co = mfma16(hr[s], R2W[s], co);
    float v = qsel(co, quad) + rb2v;
    out_full[ofull4 + (size_t)511 * 16] = v;
  }
}

extern "C" void kernel_launch(void* const* d_in, const int* in_sizes, int n_in,
                              void* d_out, int out_size, void* d_ws, size_t ws_size,
                              hipStream_t stream) {
  (void)in_sizes; (void)n_in; (void)out_size; (void)ws_size;
  const float* init_noise = (const float*)d_in[0];
  const float* dw_noise   = (const float*)d_in[1];
  const float* emb_W      = (const float*)d_in[3];
  const float* emb_b      = (const float*)d_in[4];
  const float* f_W1       = (const float*)d_in[5];
  const float* f_b1       = (const float*)d_in[6];
  const float* f_W2       = (const float*)d_in[7];
  const float* f_b2       = (const float*)d_in[8];
  const float* f_W3       = (const float*)d_in[9];
  const float* f_b3       = (const float*)d_in[10];
  const float* g_W1       = (const float*)d_in[11];
  const float* g_b1       = (const float*)d_in[12];
  const float* g_W2       = (const float*)d_in[13];
  const float* g_b2       = (const float*)d_in[14];
  const float* g_W3       = (const float*)d_in[15];
  const float* g_b3       = (const float*)d_in[16];
  const float* r_W1       = (const float*)d_in[17];
  const float* r_b1       = (const float*)d_in[18];
  const float* r_W2       = (const float*)d_in[19];
  const float* r_b2       = (const float*)d_in[20];
  float* out_full = (float*)d_out;
  float* out_match = out_full + (size_t)1024 * 512 * 16;

  hipLaunchKernelGGL(prep_kernel, dim3((PREP_TOTAL + 255) / 256), dim3(256), 0, stream,
                     f_W1, g_W1, f_W2, g_W2, f_W3, g_W3, r_W1, r_W2, emb_W, d_ws);
  hipLaunchKernelGGL(sde_main, dim3(256), dim3(512), 0, stream,
                     init_noise, dw_noise, emb_b, f_b1, f_b2, f_b3,
                     g_b1, g_b2, g_b3, r_b1, r_b2, d_ws, out_full, out_match);
}

// Round 9
// 800.669 us; speedup vs baseline: 7.9431x; 1.0816x over previous
//
#include <hip/hip_runtime.h>
#include <cmath>

// ---------------------------------------------------------------------------
// Round 14 = r13 (866us) with three barrier-gating-chain trims (one theory:
// every cycle off the serial chain has paid 1:1 for three rounds):
//  1) qsel ELIMINATED: A-frags read with real row (lane>>2)&3 (was lane&3).
//     MFMA row 4q+j -> real row q for all j, so each lane's 4 C-regs are
//     identical (row=quad) and c[0] replaces every qsel (~25-30 cndmask/step,
//     several on the tanh-input tail). Bank pattern stays 2-way (free).
//  2) P3 reorder: f-MFMA chain issued FIRST; ft computed on VALU while the
//     16 g-MFMAs execute (separate pipes); g-tanh tail after.
//  3) P2 straggler fix: wave 4's R2 block moved AFTER its dst ds_writes ->
//     its barrier-gating path equals other waves'; R2+stores trail into the
//     barrier wait.
// Base structure unchanged: 3 raw lgkm-only barriers/step, DPP reduce-scatter,
// reg-resident weights, per-lane dW register pipeline, fW3 col remap.
// ---------------------------------------------------------------------------

typedef _Float16 half8 __attribute__((ext_vector_type(8)));
typedef float floatx4 __attribute__((ext_vector_type(4)));

// ws layout: f16 region (offsets in _Float16 units)
#define H_FW1 0        // [128][64]
#define H_GW1 8192     // [128][64]
#define H_FW2 16384    // [128][128]
#define H_GW2 32768    // [128][128]
#define H_FW3 49152    // [64][128]
#define H_GW3 57344    // [512][128]
#define H_RW1 122880   // [128][64]
#define H_RW2 131072   // [16][128]  (f16 readout weights, transposed)
#define H_TOTAL 133120
// f32 region (offsets in float units from ws base; starts right after f16)
#define F_EMBT 66560             // [64][32]
#define F_W1R0F (F_EMBT + 2048)  // [128]
#define F_W1R0G (F_W1R0F + 128)  // [128]
#define F_CNT 2304
#define PREP_TOTAL (H_TOTAL + F_CNT)

__global__ void prep_kernel(const float* __restrict__ fW1, const float* __restrict__ gW1,
                            const float* __restrict__ fW2, const float* __restrict__ gW2,
                            const float* __restrict__ fW3, const float* __restrict__ gW3,
                            const float* __restrict__ rW1, const float* __restrict__ rW2,
                            const float* __restrict__ embW, void* __restrict__ ws) {
  int idx = blockIdx.x * blockDim.x + threadIdx.x;
  if (idx >= PREP_TOTAL) return;
  if (idx < H_TOTAL) {
    float v;
    if (idx < H_GW1) {
      int t = idx; int c = t >> 6, k = t & 63; v = fW1[(k + 1) * 128 + c];
    } else if (idx < H_FW2) {
      int t = idx - H_GW1; int c = t >> 6, k = t & 63; v = gW1[(k + 1) * 128 + c];
    } else if (idx < H_GW2) {
      int t = idx - H_FW2; int c = t >> 7, k = t & 127; v = fW2[k * 128 + c];
    } else if (idx < H_FW3) {
      int t = idx - H_GW2; int c = t >> 7, k = t & 127; v = gW2[k * 128 + c];
    } else if (idx < H_GW3) {
      int t = idx - H_FW3; int c = t >> 7, k = t & 127; v = fW3[k * 64 + c];
    } else if (idx < H_RW1) {
      int t = idx - H_GW3; int c = t >> 7, k = t & 127; v = gW3[k * 512 + c];
    } else if (idx < H_RW2) {
      int t = idx - H_RW1; int c = t >> 6, k = t & 63; v = rW1[k * 128 + c];
    } else {
      int t = idx - H_RW2; int c = t >> 7, k = t & 127; v = rW2[k * 16 + c];
    }
    ((_Float16*)ws)[idx] = (_Float16)v;
  } else {
    int f = idx - H_TOTAL;
    float v;
    if (f < 2048) {
      int c = f >> 5, k = f & 31; v = embW[k * 64 + c];
      ((float*)ws)[F_EMBT + f] = v;
    } else if (f < 2176) {
      ((float*)ws)[F_W1R0F + (f - 2048)] = fW1[f - 2048];
    } else {
      ((float*)ws)[F_W1R0G + (f - 2176)] = gW1[f - 2176];
    }
  }
}

__device__ __forceinline__ float sp(float x) { return __logf(1.f + __expf(x)); }

// clamp-free tanh: exp(2x)->inf gives 1-0=1; exp(2x)->0 gives 1-2=-1.
__device__ __forceinline__ float ftanh(float x) {
  float e = __expf(2.f * x);
  return 1.f - __fdividef(2.f, e + 1.f);
}

__device__ __forceinline__ floatx4 mfma16(half8 a, half8 b, floatx4 c) {
  return __builtin_amdgcn_mfma_f32_16x16x32_f16(a, b, c, 0, 0, 0);
}

// lane-linear A-layout with sub-k bank shift.
// element (m,k): seg(k>>5)*512 + subk*128 + (subk&1)*32 + m*8 + (k&7)
__device__ __forceinline__ int aofs2(int m, int k) {
  int subk = (k >> 3) & 3;
  return ((k >> 5) << 9) + (subk << 7) + ((subk & 1) << 5) + (m << 3) + (k & 7);
}

// DPP lane-permute mov (VALU pipe; no LDS). CTRL: 0xB1=xor1 (quad_perm
// [1,0,3,2]), 0x4E=xor2 ([2,3,0,1]), 0x141=row_half_mirror (l <-> 7-l
// within each aligned 8-lane group).
template <int CTRL>
__device__ __forceinline__ float dppmov(float v) {
  return __builtin_bit_cast(float,
      __builtin_amdgcn_update_dpp(0, __builtin_bit_cast(int, v), CTRL, 0xF, 0xF, true));
}

// Raw phase barrier: LDS-ordering only; vmcnt left in flight on purpose.
#define BAR()                                                    \
  do {                                                           \
    asm volatile("s_waitcnt lgkmcnt(0)" ::: "memory");           \
    __builtin_amdgcn_s_barrier();                                \
    asm volatile("" ::: "memory");                               \
  } while (0)

__global__ __launch_bounds__(512, 2)
void sde_main(const float* __restrict__ init_noise, const float* __restrict__ dw_noise,
              const float* __restrict__ emb_b,
              const float* __restrict__ f_b1, const float* __restrict__ f_b2,
              const float* __restrict__ f_b3, const float* __restrict__ g_b1,
              const float* __restrict__ g_b2, const float* __restrict__ g_b3,
              const float* __restrict__ r_b1, const float* __restrict__ r_b2,
              const void* __restrict__ ws, float* __restrict__ out_full,
              float* __restrict__ out_match) {
  // lane-linear f16 activation buffers (rows 0-3 real, duplicated reads)
  __shared__ __align__(16) _Float16 zseg[1024];                 // z, K=64
  __shared__ __align__(16) _Float16 h1f[2048], h1g[2048];       // K=128
  __shared__ __align__(16) _Float16 h2f[2048], h2g[2048];
  __shared__ __align__(16) _Float16 hrsg[2048];                 // readout hidden (f16)
  // f32 scratch (pre-loop staging only)
  __shared__ __align__(16) float zb[4 * 68];      // z0 staging
  __shared__ __align__(16) float stg[4 * 36];     // init_noise staging

  const int tid = threadIdx.x;
  const int w = tid >> 6;          // wave 0..7
  const int lane = tid & 63;
  const int ln16 = lane & 15;
  const int quad = lane >> 4;
  const int koff = quad * 8;
  const int wm = w & 3;
  const int b4 = blockIdx.x << 2;
  const _Float16* wsh = (const _Float16*)ws;
  const float* wsf = (const float*)ws;

  const float DTI = 1.0f / 511.0f;
  const float SDT = sqrtf(DTI);

  // ---- step-invariant per-lane constants (registers) ----
  const int col1 = w * 16 + ln16;                 // P1/R1 column
  const float b1fv = f_b1[col1], b1gv = g_b1[col1];
  const float w1fv = wsf[F_W1R0F + col1], w1gv = wsf[F_W1R0G + col1];
  const float rb1v = r_b1[col1];
  const int colA = wm * 32 + ln16, colB = colA + 16;  // P2 columns
  const float* bsrc2 = (w < 4) ? f_b2 : g_b2;
  const float b2vA = bsrc2[colA], b2vB = bsrc2[colB];
  // duplicated A-read offset: MFMA row r <- real row r>>2  =>  all 4 C regs
  // of a lane hold real row `quad` (c[0] usable everywhere, no qsel).
  const int ra = ((lane >> 4) << 7) + (((lane >> 4) & 1) << 5) + (((lane >> 2) & 3) << 3);
  // write addresses
  const int haddr1 = aofs2(quad, col1);
  const int haddr2A = aofs2(quad, colA), haddr2B = aofs2(quad, colB);
  // P3 z-update constants
  const int n8 = ln16 & 7;                   // noise index for this lane
  const int hlf = ln16 >> 3;                 // which half of the 16-group
  const bool writer = ((n8 & 1) == hlf);     // owner of z(quad, lstar)
  const int lstar = (w << 3) + n8;           // owned z column
  const int zwaddr = aofs2(quad, lstar);
  const int fcol = (w << 3) + n8;            // fW3 column (cols 8w..8w+7, x2)
  const float fb3v = f_b3[fcol];
  const float gb0 = g_b3[w * 64 + 0 * 16 + ln16];
  const float gb1 = g_b3[w * 64 + 1 * 16 + ln16];
  const float gb2 = g_b3[w * 64 + 2 * 16 + ln16];
  const float gb3v = g_b3[w * 64 + 3 * 16 + ln16];
  // per-lane dW source offset: dW[row=quad][n=n8]
  const int dwofs_g = (b4 + quad) * 8 + n8;
  // R2-MFMA constants (wave 4): lane (quad,ln16) stores row quad, dim ln16
  const float rb2v = r_b2[ln16];
  const size_t ofull4 = ((size_t)(b4 + quad) * 512) * 16 + ln16;
  const size_t omatch4 = ((size_t)(b4 + quad) * 64) * 16 + ln16;

  // ---- init: stage init_noise (f32) ----
  if (tid < 128) stg[(tid >> 5) * 36 + (tid & 31)] = init_noise[b4 * 32 + tid];

  // ---- persistent B-fragments (VGPR/AGPR-resident for all 511 steps) ----
  // U3: fW3 cols 8w..8w+7 duplicated (P3); R2W: rW2 tile (wave 4, P2/final)
  half8 Bf1[2], Bg1[2], Br1[2], B2[2][4], B3g[4][4], U3[4], R2W[4];
#pragma unroll
  for (int kf = 0; kf < 2; ++kf) {
    Bf1[kf] = *(const half8*)(wsh + H_FW1 + col1 * 64 + kf * 32 + koff);
    Bg1[kf] = *(const half8*)(wsh + H_GW1 + col1 * 64 + kf * 32 + koff);
    Br1[kf] = *(const half8*)(wsh + H_RW1 + col1 * 64 + kf * 32 + koff);
  }
  const _Float16* w2b = wsh + (w < 4 ? H_FW2 : H_GW2);
#pragma unroll
  for (int i2 = 0; i2 < 2; ++i2)
#pragma unroll
    for (int kf = 0; kf < 4; ++kf)
      B2[i2][kf] = *(const half8*)(w2b + ((wm * 2 + i2) * 16 + ln16) * 128 + kf * 32 + koff);
#pragma unroll
  for (int i2 = 0; i2 < 4; ++i2)
#pragma unroll
    for (int kf = 0; kf < 4; ++kf)
      B3g[i2][kf] = *(const half8*)(wsh + H_GW3 + ((w * 4 + i2) * 16 + ln16) * 128 + kf * 32 + koff);
#pragma unroll
  for (int kf = 0; kf < 4; ++kf) {
    U3[kf] = *(const half8*)(wsh + H_FW3 + fcol * 128 + kf * 32 + koff);
    R2W[kf] = *(const half8*)(wsh + H_RW2 + ln16 * 128 + kf * 32 + koff);
  }
  __syncthreads();

  // ---- z0 = init_noise @ emb_W + emb_b ----
  if (tid < 256) {
    const int rr = tid & 3, l = tid >> 2;
    const float* pe = wsf + F_EMBT + l * 32;
    float acc = emb_b[l];
#pragma unroll
    for (int c = 0; c < 8; ++c) {
      float4 a = *(const float4*)(&stg[rr * 36 + 4 * c]);
      float4 v = *(const float4*)(pe + 4 * c);
      acc += a.x * v.x + a.y * v.y + a.z * v.z + a.w * v.w;
    }
    zb[rr * 68 + l] = acc;
    zseg[aofs2(rr, l)] = (_Float16)acc;
  }
  __syncthreads();

  // z f32 state lives in the owner lane's register
  float zreg = writer ? zb[quad * 68 + lstar] : 0.f;

  // per-lane dW register pipeline: dwv = step i's weight (incl. SDT)
  float dwv = dw_noise[dwofs_g] * SDT;
  float dwn = 0.f;

#pragma unroll 1
  for (int i = 0; i < 511; ++i) {
    const float t_s = (float)i * DTI;

    // ---- P1: L1 (f,g) + R1 sharing z A-frags; issue dW(i+1) load ----
    {
      half8 a0 = *(const half8*)(&zseg[ra]);
      half8 a1 = *(const half8*)(&zseg[512 + ra]);
      {
        int ip = (i < 510) ? i + 1 : 510;
        dwn = dw_noise[(size_t)ip * 8192 + dwofs_g];
      }
      floatx4 cf = {0.f, 0.f, 0.f, 0.f}, cg = {0.f, 0.f, 0.f, 0.f}, cr = {0.f, 0.f, 0.f, 0.f};
      cf = mfma16(a0, Bf1[0], cf); cf = mfma16(a1, Bf1[1], cf);
      cg = mfma16(a0, Bg1[0], cg); cg = mfma16(a1, Bg1[1], cg);
      cr = mfma16(a0, Br1[0], cr); cr = mfma16(a1, Br1[1], cr);
      h1f[haddr1] = (_Float16)sp(cf[0] + b1fv + t_s * w1fv);
      h1g[haddr1] = (_Float16)sp(cg[0] + b1gv + t_s * w1gv);
      hrsg[haddr1] = (_Float16)fmaxf(cr[0] + rb1v, 0.f);
    }
    BAR();

    // ---- P2: L2 (waves 0-3 f, 4-7 g); R2-MFMA (wave 4) AFTER dst writes ----
    {
      const _Float16* asrc = (w < 4) ? h1f : h1g;
      half8 a[4];
#pragma unroll
      for (int s = 0; s < 4; ++s) a[s] = *(const half8*)(&asrc[s * 512 + ra]);
      floatx4 c0 = {0.f, 0.f, 0.f, 0.f}, c1 = {0.f, 0.f, 0.f, 0.f};
#pragma unroll
      for (int s = 0; s < 4; ++s) {
        c0 = mfma16(a[s], B2[0][s], c0);
        c1 = mfma16(a[s], B2[1][s], c1);
      }
      _Float16* dst = (w < 4) ? h2f : h2g;
      dst[haddr2A] = (_Float16)sp(c0[0] + b2vA);
      dst[haddr2B] = (_Float16)sp(c1[0] + b2vB);
      if (w == 4) {  // after the barrier-gating writes: trails into the wait
        half8 hr[4];
#pragma unroll
        for (int s = 0; s < 4; ++s) hr[s] = *(const half8*)(&hrsg[s * 512 + ra]);
        floatx4 co = {0.f, 0.f, 0.f, 0.f};
#pragma unroll
        for (int s = 0; s < 4; ++s) co = mfma16(hr[s], R2W[s], co);
        float v = co[0] + rb2v;
        out_full[ofull4 + (size_t)i * 16] = v;
        if ((i & 7) == 0) out_match[omatch4 + (size_t)(i >> 3) * 16] = v;
      }
    }
    BAR();

    // ---- P3: L3 f FIRST (ft on VALU under g-MFMAs), L3 g, fused z-update ----
    {
      // f-chain: two independent 2-MFMA chains, issued first
      floatx4 cfa = {0.f, 0.f, 0.f, 0.f}, cfb = {0.f, 0.f, 0.f, 0.f};
      {
        half8 af0 = *(const half8*)(&h2f[0 * 512 + ra]);
        half8 af1 = *(const half8*)(&h2f[1 * 512 + ra]);
        half8 af2 = *(const half8*)(&h2f[2 * 512 + ra]);
        half8 af3 = *(const half8*)(&h2f[3 * 512 + ra]);
        cfa = mfma16(af0, U3[0], cfa); cfa = mfma16(af1, U3[1], cfa);
        cfb = mfma16(af2, U3[2], cfb); cfb = mfma16(af3, U3[3], cfb);
      }
      half8 ag[4];
#pragma unroll
      for (int s = 0; s < 4; ++s) ag[s] = *(const half8*)(&h2g[s * 512 + ra]);
      floatx4 cg4[4];
#pragma unroll
      for (int i2 = 0; i2 < 4; ++i2) cg4[i2] = (floatx4){0.f, 0.f, 0.f, 0.f};
#pragma unroll
      for (int s = 0; s < 4; ++s)
#pragma unroll
        for (int i2 = 0; i2 < 4; ++i2) cg4[i2] = mfma16(ag[s], B3g[i2][s], cg4[i2]);
      // f-term on VALU while g-MFMAs execute (independent pipes)
      float ft = ftanh(cfa[0] + cfb[0] + fb3v) * DTI;
      // weighted g-terms, one per i2 (dwv = dW[quad][n8]*SDT, register)
      float v0 = ftanh(cg4[0][0] + gb0) * dwv;
      float v1 = ftanh(cg4[1][0] + gb1) * dwv;
      float v2 = ftanh(cg4[2][0] + gb2) * dwv;
      float v3 = ftanh(cg4[3][0] + gb3v) * dwv;
      // DPP reduce-scatter over 8-lane group (VALU-only, no LDS):
      float s0 = (n8 & 4) ? v0 : v2;
      float s1 = (n8 & 4) ? v1 : v3;
      float pa = ((n8 & 4) ? v2 : v0) + dppmov<0x141>(s0);
      float pb = ((n8 & 4) ? v3 : v1) + dppmov<0x141>(s1);
      float u = (n8 & 2) ? pa : pb;
      float sv = ((n8 & 2) ? pb : pa) + dppmov<0x4E>(u);
      float S = sv + dppmov<0xB1>(sv);
      if (writer) {
        zreg += S + ft;
        zseg[zwaddr] = (_Float16)zreg;
      }
    }
    BAR();

    dwv = dwn * SDT;  // step i+1's weight (load issued back in P1, hidden)
  }

  // ---- final readout T=511 ----
  {
    half8 a0 = *(const half8*)(&zseg[ra]);
    half8 a1 = *(const half8*)(&zseg[512 + ra]);
    floatx4 cr = {0.f, 0.f, 0.f, 0.f};
    cr = mfma16(a0, Br1[0], cr); cr = mfma16(a1, Br1[1], cr);
    hrsg[haddr1] = (_Float16)fmaxf(cr[0] + rb1v, 0.f);
  }
  BAR();
  if (w == 4) {
    half8 hr[4];
#pragma unroll
    for (int s = 0; s < 4; ++s) hr[s] = *(const half8*)(&hrsg[s * 512 + ra]);
    floatx4 co = {0.f, 0.f, 0.f, 0.f};
#pragma unroll
    for (int s = 0; s < 4; ++s) co = mfma16(hr[s], R2W[s], co);
    float v = co[0] + rb2v;
    out_full[ofull4 + (size_t)511 * 16] = v;
  }
}

extern "C" void kernel_launch(void* const* d_in, const int* in_sizes, int n_in,
                              void* d_out, int out_size, void* d_ws, size_t ws_size,
                              hipStream_t stream) {
  (void)in_sizes; (void)n_in; (void)out_size; (void)ws_size;
  const float* init_noise = (const float*)d_in[0];
  const float* dw_noise   = (const float*)d_in[1];
  const float* emb_W      = (const float*)d_in[3];
  const float* emb_b      = (const float*)d_in[4];
  const float* f_W1       = (const float*)d_in[5];
  const float* f_b1       = (const float*)d_in[6];
  const float* f_W2       = (const float*)d_in[7];
  const float* f_b2       = (const float*)d_in[8];
  const float* f_W3       = (const float*)d_in[9];
  const float* f_b3       = (const float*)d_in[10];
  const float* g_W1       = (const float*)d_in[11];
  const float* g_b1       = (const float*)d_in[12];
  const float* g_W2       = (const float*)d_in[13];
  const float* g_b2       = (const float*)d_in[14];
  const float* g_W3       = (const float*)d_in[15];
  const float* g_b3       = (const float*)d_in[16];
  const float* r_W1       = (const float*)d_in[17];
  const float* r_b1       = (const float*)d_in[18];
  const float* r_W2       = (const float*)d_in[19];
  const float* r_b2       = (const float*)d_in[20];
  float* out_full = (float*)d_out;
  float* out_match = out_full + (size_t)1024 * 512 * 16;

  hipLaunchKernelGGL(prep_kernel, dim3((PREP_TOTAL + 255) / 256), dim3(256), 0, stream,
                     f_W1, g_W1, f_W2, g_W2, f_W3, g_W3, r_W1, r_W2, emb_W, d_ws);
  hipLaunchKernelGGL(sde_main, dim3(256), dim3(512), 0, stream,
                     init_noise, dw_noise, emb_b, f_b1, f_b2, f_b3,
                     g_b1, g_b2, g_b3, r_b1, r_b2, d_ws, out_full, out_match);
}